// Round 1
// baseline (1921.170 us; speedup 1.0000x reference)
//
#include <hip/hip_runtime.h>

typedef __attribute__((ext_vector_type(8))) unsigned short u16x8;

#define NPTS 400000
#define HW 32400
#define WID 180
#define NCI 256
#define NCO 64
#define NSEG 2560
#define NINST 256

__device__ __forceinline__ float bf2f(unsigned short u) {
  union { unsigned int i; float f; } v; v.i = ((unsigned int)u) << 16; return v.f;
}
__device__ __forceinline__ unsigned short f2bf(float f) {
  unsigned int u = __float_as_uint(f);
  return (unsigned short)((u + 0x7fffu + ((u >> 16) & 1u)) >> 16);
}

// ---------------- K1: direct 3x3 SAME conv, fp32 ----------------
// block = 256 threads = 16x16 pixel tile; 32 output channels per block.
// Weights at wave-uniform addresses -> scalar loads; 288 FMA per 9 input loads.
__global__ __launch_bounds__(256) void k_conv(const float* __restrict__ x,
                                              const float* __restrict__ wt,
                                              float* __restrict__ y) {
  const int tile = blockIdx.x;   // 0..143 (12x12 tiles of 16x16 covering 180x180)
  const int cog  = blockIdx.y;   // 0..1
  const int b    = blockIdx.z;   // 0..3
  const int tx = threadIdx.x & 15, ty = threadIdx.x >> 4;
  const int h = (tile / 12) * 16 + ty;
  const int wcol = (tile % 12) * 16 + tx;
  const bool valid = (h < WID) && (wcol < WID);
  int off[9]; float msk[9];
#pragma unroll
  for (int kh = 0; kh < 3; ++kh)
#pragma unroll
    for (int kw = 0; kw < 3; ++kw) {
      int hh = h + kh - 1, ww = wcol + kw - 1;
      bool inb = valid && (hh >= 0) && (hh < WID) && (ww >= 0) && (ww < WID);
      off[kh * 3 + kw] = inb ? hh * WID + ww : 0;
      msk[kh * 3 + kw] = inb ? 1.0f : 0.0f;
    }
  float acc[32];
#pragma unroll
  for (int c = 0; c < 32; ++c) acc[c] = 0.0f;
  const float* xb = x + (size_t)b * NCI * HW;
  const float* wb = wt + (size_t)(cog * 32) * NCI * 9;
  for (int ci = 0; ci < NCI; ++ci) {
    const float* xp = xb + (size_t)ci * HW;
    float in[9];
#pragma unroll
    for (int k = 0; k < 9; ++k) in[k] = xp[off[k]] * msk[k];
    const float* wr = wb + ci * 9;
#pragma unroll
    for (int c = 0; c < 32; ++c) {
      const float* wc = wr + c * (NCI * 9);
#pragma unroll
      for (int k = 0; k < 9; ++k) acc[c] = fmaf(in[k], wc[k], acc[c]);
    }
  }
  if (valid) {
    float* yp = y + ((size_t)b * NCO + cog * 32) * HW + h * WID + wcol;
#pragma unroll
    for (int c = 0; c < 32; ++c) yp[(size_t)c * HW] = acc[c];
  }
}

// ---------------- K2: per-(channel,batch) partial BN stats ----------------
__global__ void k_stats(const float* __restrict__ y, float* __restrict__ part) {
  const int c = blockIdx.x, b = blockIdx.y;
  const float* p = y + ((size_t)b * NCO + c) * HW;
  float s = 0.f, ss = 0.f;
  for (int i = threadIdx.x; i < HW; i += 256) { float v = p[i]; s += v; ss = fmaf(v, v, ss); }
  __shared__ float ls[256], lss[256];
  ls[threadIdx.x] = s; lss[threadIdx.x] = ss;
  __syncthreads();
  for (int st = 128; st > 0; st >>= 1) {
    if (threadIdx.x < st) { ls[threadIdx.x] += ls[threadIdx.x + st]; lss[threadIdx.x] += lss[threadIdx.x + st]; }
    __syncthreads();
  }
  if (threadIdx.x == 0) { part[(c * 4 + b) * 2] = ls[0]; part[(c * 4 + b) * 2 + 1] = lss[0]; }
}

// ---------------- K3: BN apply + ReLU + NCHW -> (b,h,w,c) bf16 ----------------
__global__ void k_bn(const float* __restrict__ y, const float* __restrict__ part,
                     const float* __restrict__ gamma, const float* __restrict__ beta,
                     unsigned short* __restrict__ bev) {
  __shared__ float sa[64], sb[64];
  const int t = threadIdx.x;
  if (t < 64) {
    float s = 0.f, ss = 0.f;
    for (int b = 0; b < 4; ++b) { s += part[(t * 4 + b) * 2]; ss += part[(t * 4 + b) * 2 + 1]; }
    float mu = s / 129600.f;
    float var = ss / 129600.f - mu * mu;
    float rs = rsqrtf(var + 1e-5f);
    float a = rs * gamma[t];
    sa[t] = a; sb[t] = beta[t] - mu * a;
  }
  __syncthreads();
  const int id = blockIdx.x * 256 + t;
  if (id >= 4 * HW) return;
  const int b = id / HW, hw = id % HW;
  const float* yp = y + (size_t)b * NCO * HW + hw;
  unsigned short* op = bev + (size_t)id * 64;
  for (int c0 = 0; c0 < 64; c0 += 8) {
    u16x8 pack;
#pragma unroll
    for (int k = 0; k < 8; ++k) {
      int c = c0 + k;
      float v = fmaf(yp[(size_t)c * HW], sa[c], sb[c]);
      v = v > 0.f ? v : 0.f;
      pack[k] = f2bf(v);
    }
    *(u16x8*)(op + c0) = pack;
  }
}

// ---------------- K4: bilinear sample, wave-per-point, lane=channel ----------------
__global__ void k_points(const float* __restrict__ pts, const unsigned short* __restrict__ bev,
                         unsigned short* __restrict__ pf, int* __restrict__ seg) {
  const int gid = blockIdx.x * blockDim.x + threadIdx.x;
  const int lane = gid & 63;
  const int wid = gid >> 6;
  const int nw = (gridDim.x * blockDim.x) >> 6;
  for (int p = wid; p < NPTS; p += nw) {
    const float* pr = pts + (size_t)p * 9;
    float pbf = pr[0], xx = pr[1], yy = pr[2];
    float swf = pr[6], insf = pr[7];
    int b = (int)pbf;
    float px = (xx - (-54.0f)) / 0.6f;
    float py = (yy - (-54.0f)) / 0.6f;
    int x0 = (int)floorf(px); x0 = min(max(x0, 0), WID - 1);
    int x1 = min(x0 + 1, WID - 1);
    int y0 = (int)floorf(py); y0 = min(max(y0, 0), WID - 1);
    int y1 = min(y0 + 1, WID - 1);
    float x0f = (float)x0, x1f = (float)x1, y0f = (float)y0, y1f = (float)y1;
    float wa = (x1f - px) * (y1f - py);
    float wb = (x1f - px) * (py - y0f);
    float wc = (px - x0f) * (y1f - py);
    float wd = (px - x0f) * (py - y0f);
    float Ia = bf2f(bev[(size_t)((b * WID + y0) * WID + x0) * 64 + lane]);
    float Ib = bf2f(bev[(size_t)((b * WID + y1) * WID + x0) * 64 + lane]);
    float Ic = bf2f(bev[(size_t)((b * WID + y0) * WID + x1) * 64 + lane]);
    float Id = bf2f(bev[(size_t)((b * WID + y1) * WID + x1) * 64 + lane]);
    float f = wa * Ia + wb * Ib + wc * Ic + wd * Id;
    pf[(size_t)p * 64 + lane] = f2bf(f);
    if (lane == 0) seg[p] = (b * 64 + (int)insf) * 10 + (int)swf;
  }
}

// ---------------- K4b: point heads (cls/offset/embedding) ----------------
__global__ void k_heads(const unsigned short* __restrict__ pf,
                        const float* __restrict__ wseg, const float* __restrict__ bseg,
                        const float* __restrict__ wreg, const float* __restrict__ breg,
                        const float* __restrict__ wemb, const float* __restrict__ bemb,
                        float* __restrict__ ocls, float* __restrict__ ooff, float* __restrict__ oemb) {
  const int p = blockIdx.x * 256 + threadIdx.x;
  if (p >= NPTS) return;
  float a0 = bseg[0], a1 = bseg[1], a2 = bseg[2];
  float r0 = breg[0], r1 = breg[1], r2 = breg[2];
  float e0 = bemb[0], e1 = bemb[1];
  const u16x8* q = (const u16x8*)(pf + (size_t)p * 64);
#pragma unroll
  for (int g = 0; g < 8; ++g) {
    u16x8 v8 = q[g];
#pragma unroll
    for (int k = 0; k < 8; ++k) {
      int kk = g * 8 + k;
      float v = bf2f(v8[k]);
      a0 = fmaf(v, wseg[kk * 3 + 0], a0);
      a1 = fmaf(v, wseg[kk * 3 + 1], a1);
      a2 = fmaf(v, wseg[kk * 3 + 2], a2);
      r0 = fmaf(v, wreg[kk * 3 + 0], r0);
      r1 = fmaf(v, wreg[kk * 3 + 1], r1);
      r2 = fmaf(v, wreg[kk * 3 + 2], r2);
      e0 = fmaf(v, wemb[kk * 2 + 0], e0);
      e1 = fmaf(v, wemb[kk * 2 + 1], e1);
    }
  }
  ocls[p * 3 + 0] = a0; ocls[p * 3 + 1] = a1; ocls[p * 3 + 2] = a2;
  ooff[p * 3 + 0] = r0; ooff[p * 3 + 1] = r1; ooff[p * 3 + 2] = r2;
  oemb[p * 2 + 0] = e0; oemb[p * 2 + 1] = e1;
}

// ---------------- K5/K6/K7: counting sort by segment ----------------
__global__ void k_hist(const int* __restrict__ seg, int* __restrict__ cnt) {
  const int p = blockIdx.x * 256 + threadIdx.x;
  if (p < NPTS) atomicAdd(&cnt[seg[p]], 1);
}

__global__ void k_scan(const int* __restrict__ cnt, int* __restrict__ base, int* __restrict__ cursor) {
  __shared__ int csum[256];
  const int t = threadIdx.x;
  int loc[10]; int run = 0;
#pragma unroll
  for (int k = 0; k < 10; ++k) { loc[k] = cnt[t * 10 + k]; run += loc[k]; }
  csum[t] = run;
  __syncthreads();
  if (t == 0) {
    int acc = 0;
    for (int i = 0; i < 256; ++i) { int v = csum[i]; csum[i] = acc; acc += v; }
  }
  __syncthreads();
  int acc = csum[t];
#pragma unroll
  for (int k = 0; k < 10; ++k) {
    int idx = t * 10 + k;
    base[idx] = acc; cursor[idx] = acc;
    acc += loc[k];
  }
}

__global__ void k_scatter(const int* __restrict__ seg, int* __restrict__ cursor, int* __restrict__ order) {
  const int p = blockIdx.x * 256 + threadIdx.x;
  if (p < NPTS) {
    int pos = atomicAdd(&cursor[seg[p]], 1);
    order[pos] = p;
  }
}

// ---------------- K8: per-segment centroid + shape_enc max + feat max ----------------
__global__ void k_seg(const int* __restrict__ cnt, const int* __restrict__ base,
                      const int* __restrict__ order, const float* __restrict__ pts,
                      const unsigned short* __restrict__ pf,
                      const float* __restrict__ wsh, const float* __restrict__ bsh,
                      float* __restrict__ lf, float* __restrict__ centroid,
                      int* __restrict__ nonempty) {
  const int s = blockIdx.x;
  const int t = threadIdx.x; // 64 threads
  const int n = cnt[s];
  const int bs = base[s];
  float sx = 0.f, sy = 0.f, sz = 0.f;
  for (int i = t; i < n; i += 64) {
    int p = order[bs + i];
    const float* pr = pts + (size_t)p * 9;
    sx += pr[1]; sy += pr[2]; sz += pr[3];
  }
#pragma unroll
  for (int m = 32; m > 0; m >>= 1) {
    sx += __shfl_xor(sx, m); sy += __shfl_xor(sy, m); sz += __shfl_xor(sz, m);
  }
  float dn = (float)max(n, 1);
  float cx = sx / dn, cy = sy / dn, cz = sz / dn;
  float w0 = wsh[t], w1 = wsh[64 + t], w2 = wsh[128 + t], bb = bsh[t];
  float smax = -INFINITY, lmax = -INFINITY;
  for (int i = 0; i < n; ++i) {
    int p = order[bs + i];
    const float* pr = pts + (size_t)p * 9;
    float c0 = pr[1] - cx, c1 = pr[2] - cy, c2 = pr[3] - cz;
    float sv = fmaf(c0, w0, fmaf(c1, w1, fmaf(c2, w2, bb)));
    smax = fmaxf(smax, sv);
    lmax = fmaxf(lmax, bf2f(pf[(size_t)p * 64 + t]));
  }
  bool ne = n > 0;
  lf[s * 64 + t] = (ne ? lmax : 0.f) + (ne ? smax : 0.f);
  if (t == 0) {
    nonempty[s] = ne ? 1 : 0;
    centroid[s * 3 + 0] = cx; centroid[s * 3 + 1] = cy; centroid[s * 3 + 2] = cz;
  }
}

// ---------------- K9: per-instance globals + sweep min/max + inst_mos ----------------
__global__ void k_glob(const float* __restrict__ lf, const int* __restrict__ ne,
                       const float* __restrict__ centroid,
                       const float* __restrict__ wmos, const float* __restrict__ bmos,
                       float* __restrict__ gf, float* __restrict__ tc, float* __restrict__ ic,
                       float* __restrict__ omos) {
  const int i = blockIdx.x;
  const int t = threadIdx.x; // 64 threads
  float g = -INFINITY;
  int maxsw = -1, minsw = 10;
  bool any = false;
#pragma unroll
  for (int s = 0; s < 10; ++s) {
    int idx = i * 10 + s;
    bool e = ne[idx] != 0;
    float v = lf[idx * 64 + t];
    g = fmaxf(g, e ? v : -INFINITY);
    if (e) { any = true; maxsw = s; minsw = min(minsw, s); }
  }
  float gv = any ? g : 0.f;
  gf[i * 64 + t] = gv;
  int idxmax = min(max(i * 10 + maxsw, 0), NSEG - 1);
  int idxmin = min(max(i * 10 + minsw, 0), NSEG - 1);
  float tcx = centroid[idxmax * 3 + 0], tcy = centroid[idxmax * 3 + 1], tcz = centroid[idxmax * 3 + 2];
  float icx = centroid[idxmin * 3 + 0], icy = centroid[idxmin * 3 + 1], icz = centroid[idxmin * 3 + 2];
  if (t == 0) {
    tc[i * 3 + 0] = tcx; tc[i * 3 + 1] = tcy; tc[i * 3 + 2] = tcz;
    ic[i * 3 + 0] = icx; ic[i * 3 + 1] = icy; ic[i * 3 + 2] = icz;
  }
  float r = gv * wmos[t];
#pragma unroll
  for (int m = 32; m > 0; m >>= 1) r += __shfl_xor(r, m);
  if (t == 0) {
    r += icx * wmos[64] + icy * wmos[65] + icz * wmos[66];
    r += tcx * wmos[67] + tcy * wmos[68] + tcz * wmos[69];
    omos[i] = r + bmos[0];
  }
}

// ---------------- K10: locals_tf = locals_cat(134) @ w_tf(134x7) ----------------
__global__ void k_tf(const float* __restrict__ lf, const float* __restrict__ gf,
                     const float* __restrict__ centroid, const float* __restrict__ tc,
                     const float* __restrict__ wtf, const float* __restrict__ btf,
                     float* __restrict__ otf) {
  const int r = blockIdx.x * 256 + threadIdx.x;
  if (r >= NSEG) return;
  const int i = r / 10;
  float acc[7];
#pragma unroll
  for (int j = 0; j < 7; ++j) acc[j] = btf[j];
  for (int k = 0; k < 64; ++k) {
    float v = lf[r * 64 + k];
#pragma unroll
    for (int j = 0; j < 7; ++j) acc[j] = fmaf(v, wtf[k * 7 + j], acc[j]);
  }
  for (int k = 0; k < 64; ++k) {
    float v = gf[i * 64 + k];
#pragma unroll
    for (int j = 0; j < 7; ++j) acc[j] = fmaf(v, wtf[(64 + k) * 7 + j], acc[j]);
  }
#pragma unroll
  for (int c = 0; c < 3; ++c) {
    float v = centroid[r * 3 + c];
#pragma unroll
    for (int j = 0; j < 7; ++j) acc[j] = fmaf(v, wtf[(128 + c) * 7 + j], acc[j]);
  }
#pragma unroll
  for (int c = 0; c < 3; ++c) {
    float v = tc[i * 3 + c];
#pragma unroll
    for (int j = 0; j < 7; ++j) acc[j] = fmaf(v, wtf[(131 + c) * 7 + j], acc[j]);
  }
#pragma unroll
  for (int j = 0; j < 7; ++j) otf[r * 7 + j] = acc[j];
}

extern "C" void kernel_launch(void* const* d_in, const int* in_sizes, int n_in,
                              void* d_out, int out_size, void* d_ws, size_t ws_size,
                              hipStream_t stream) {
  const float* pts   = (const float*)d_in[0];
  const float* x     = (const float*)d_in[1];
  const float* convw = (const float*)d_in[2];
  const float* gamma = (const float*)d_in[3];
  const float* beta  = (const float*)d_in[4];
  const float* wseg  = (const float*)d_in[5];
  const float* bseg  = (const float*)d_in[6];
  const float* wreg  = (const float*)d_in[7];
  const float* breg  = (const float*)d_in[8];
  const float* wemb  = (const float*)d_in[9];
  const float* bemb  = (const float*)d_in[10];
  const float* wsh   = (const float*)d_in[11];
  const float* bsh   = (const float*)d_in[12];
  const float* wtf   = (const float*)d_in[13];
  const float* btf   = (const float*)d_in[14];
  const float* wmos  = (const float*)d_in[15];
  const float* bmos  = (const float*)d_in[16];

  float* out = (float*)d_out;
  float* o_cls = out;                 // 400000 x 3
  float* o_off = out + 1200000;       // 400000 x 3
  float* o_emb = out + 2400000;       // 400000 x 2
  float* o_tf  = out + 3200000;       // 2560 x 7
  float* o_mos = out + 3217920;       // 256 x 1

  char* wsp = (char*)d_ws;
  size_t off = 0;
  auto alloc = [&](size_t bytes) -> void* {
    void* p = wsp + off;
    off = (off + bytes + 255) & ~(size_t)255;
    return p;
  };
  float*          y        = (float*)alloc((size_t)4 * 64 * HW * 4);       // 33.2 MB
  unsigned short* bev      = (unsigned short*)alloc((size_t)4 * HW * 64 * 2); // 16.6 MB
  unsigned short* pf       = (unsigned short*)alloc((size_t)NPTS * 64 * 2);   // 51.2 MB
  int*            seg      = (int*)alloc((size_t)NPTS * 4);
  int*            order    = (int*)alloc((size_t)NPTS * 4);
  int*            cnt      = (int*)alloc(NSEG * 4);
  int*            base     = (int*)alloc(NSEG * 4);
  int*            cursor   = (int*)alloc(NSEG * 4);
  float*          part     = (float*)alloc(64 * 4 * 2 * 4);
  float*          centroid = (float*)alloc(NSEG * 3 * 4);
  float*          lf       = (float*)alloc(NSEG * 64 * 4);
  int*            nonem    = (int*)alloc(NSEG * 4);
  float*          gf       = (float*)alloc(NINST * 64 * 4);
  float*          tc       = (float*)alloc(NINST * 3 * 4);
  float*          ic       = (float*)alloc(NINST * 3 * 4);
  (void)ws_size; (void)n_in; (void)in_sizes; (void)out_size;

  hipMemsetAsync(cnt, 0, NSEG * 4, stream);

  k_conv<<<dim3(144, 2, 4), 256, 0, stream>>>(x, convw, y);
  k_stats<<<dim3(64, 4), 256, 0, stream>>>(y, part);
  k_bn<<<(4 * HW + 255) / 256, 256, 0, stream>>>(y, part, gamma, beta, bev);
  k_points<<<1024, 256, 0, stream>>>(pts, bev, pf, seg);
  k_heads<<<(NPTS + 255) / 256, 256, 0, stream>>>(pf, wseg, bseg, wreg, breg, wemb, bemb,
                                                  o_cls, o_off, o_emb);
  k_hist<<<(NPTS + 255) / 256, 256, 0, stream>>>(seg, cnt);
  k_scan<<<1, 256, 0, stream>>>(cnt, base, cursor);
  k_scatter<<<(NPTS + 255) / 256, 256, 0, stream>>>(seg, cursor, order);
  k_seg<<<NSEG, 64, 0, stream>>>(cnt, base, order, pts, pf, wsh, bsh, lf, centroid, nonem);
  k_glob<<<NINST, 64, 0, stream>>>(lf, nonem, centroid, wmos, bmos, gf, tc, ic, o_mos);
  k_tf<<<(NSEG + 255) / 256, 256, 0, stream>>>(lf, gf, centroid, tc, wtf, btf, o_tf);
}

// Round 2
// 540.550 us; speedup vs baseline: 3.5541x; 3.5541x over previous
//
#include <hip/hip_runtime.h>

typedef __attribute__((ext_vector_type(8))) unsigned short u16x8;
typedef __attribute__((ext_vector_type(8))) short s16x8;
typedef __attribute__((ext_vector_type(4))) float f32x4;

#define NPTS 400000
#define HW 32400
#define WID 180
#define NCI 256
#define NCO 64
#define NSEG 2560
#define NINST 256

__device__ __forceinline__ float bf2f(unsigned short u) {
  union { unsigned int i; float f; } v; v.i = ((unsigned int)u) << 16; return v.f;
}
__device__ __forceinline__ unsigned short f2bf(float f) {
  unsigned int u = __float_as_uint(f);
  return (unsigned short)((u + 0x7fffu + ((u >> 16) & 1u)) >> 16);
}

// ---------------- K0: NCHW fp32 -> NHWC bf16 transpose ----------------
// block: 64 w x 64 ci tile for one (b,h). LDS-staged, coalesced both sides.
__global__ __launch_bounds__(256) void k_transpose(const float* __restrict__ x,
                                                   unsigned short* __restrict__ xt) {
  const int bw = blockIdx.x;            // 0..11: wtile = bw>>2, citile = bw&3
  const int h = blockIdx.y, b = blockIdx.z;
  const int w0 = (bw >> 2) * 64, ci0 = (bw & 3) * 64;
  __shared__ float tile[64][66];
  const int tid = threadIdx.x;
  const int tx = tid & 63, ty = tid >> 6;
  for (int cc = 0; cc < 16; ++cc) {
    int cl = cc * 4 + ty;
    float v = 0.f;
    int w = w0 + tx;
    if (w < WID) v = x[((size_t)(b * NCI + ci0 + cl) * WID + h) * WID + w];
    tile[tx][cl] = v;
  }
  __syncthreads();
  const int tx2 = tid & 31, ty2 = tid >> 5;
  for (int pp = 0; pp < 8; ++pp) {
    int wl = pp * 8 + ty2;
    int w = w0 + wl;
    if (w >= WID) continue;
    float f0 = tile[wl][2 * tx2], f1 = tile[wl][2 * tx2 + 1];
    unsigned int packed = (unsigned int)f2bf(f0) | ((unsigned int)f2bf(f1) << 16);
    *(unsigned int*)(xt + ((size_t)((b * WID + h) * WID + w)) * NCI + ci0 + 2 * tx2) = packed;
  }
}

// ---------------- K0b: conv_w [64][256][3][3] f32 -> wb[tap][co][ci] bf16 ----------------
__global__ void k_wreorg(const float* __restrict__ wt, unsigned short* __restrict__ wb) {
  int id = blockIdx.x * 256 + threadIdx.x;
  if (id >= 9 * 64 * 256) return;
  int ci = id & 255, co = (id >> 8) & 63, tap = id >> 14;
  wb[id] = f2bf(wt[((size_t)co * 256 + ci) * 9 + tap]);
}

// ---------------- K1: implicit-GEMM conv via MFMA bf16 ----------------
// block = (h, w-half, b); M=96 pixels x N=64 co, K=2304 (4 ci-chunks x 9 taps x 2).
// LDS strip: 3 rows x 98 px x 64 ci bf16, XOR-swizzled (T2) for conflict-free A-reads.
__global__ __launch_bounds__(256) void k_conv_mfma(const unsigned short* __restrict__ xt,
                                                   const unsigned short* __restrict__ wb,
                                                   unsigned short* __restrict__ y) {
  const int h = blockIdx.x;       // 0..179
  const int wth = blockIdx.y;     // 0..1
  const int b = blockIdx.z;       // 0..3
  const int w0 = wth * 96;
  __shared__ unsigned char strip[3 * 98 * 128];
  const int tid = threadIdx.x;
  const int lane = tid & 63, wv = tid >> 6;
  const int mh = wv >> 1, nh = wv & 1;
  const int l15 = lane & 15, lk = lane >> 4;

  f32x4 acc[3][2];
#pragma unroll
  for (int i = 0; i < 3; ++i)
#pragma unroll
    for (int j = 0; j < 2; ++j) { acc[i][j][0] = 0.f; acc[i][j][1] = 0.f; acc[i][j][2] = 0.f; acc[i][j][3] = 0.f; }

  for (int chunk = 0; chunk < 4; ++chunk) {
    if (chunk) __syncthreads();
    // stage 3 x 98 x 64ci bf16 (16B per thread-iter), swizzled
    for (int i = tid; i < 3 * 98 * 8; i += 256) {
      int dh = i / (98 * 8); int rem = i - dh * (98 * 8);
      int w = rem >> 3, s = rem & 7;
      int hh = h + dh - 1;
      int worig = w0 + w - 1;
      u16x8 v = {0, 0, 0, 0, 0, 0, 0, 0};
      if (hh >= 0 && hh < WID && worig >= 0 && worig < WID) {
        const unsigned short* g = xt + ((size_t)((b * WID + hh) * WID + worig)) * NCI + chunk * 64 + s * 8;
        v = *(const u16x8*)g;
      }
      *(u16x8*)(strip + (dh * 98 + w) * 128 + ((s * 16) ^ ((w & 7) << 4))) = v;
    }
    __syncthreads();
    for (int tap = 0; tap < 9; ++tap) {
      const int dh = tap / 3, dw = tap % 3;
      const unsigned short* wbase = wb + (size_t)tap * 64 * 256 + chunk * 64;
#pragma unroll
      for (int kk = 0; kk < 2; ++kk) {
        s16x8 bfr[2];
#pragma unroll
        for (int nf = 0; nf < 2; ++nf) {
          int co = (nh * 2 + nf) * 16 + l15;
          bfr[nf] = *(const s16x8*)(wbase + (size_t)co * 256 + kk * 32 + lk * 8);
        }
        s16x8 afr[3];
#pragma unroll
        for (int i = 0; i < 3; ++i) {
          int wp = (mh * 3 + i) * 16 + l15 + dw;
          int byte = (dh * 98 + wp) * 128 + ((kk * 64 + lk * 16) ^ ((wp & 7) << 4));
          afr[i] = *(const s16x8*)(strip + byte);
        }
#pragma unroll
        for (int i = 0; i < 3; ++i)
#pragma unroll
          for (int nf = 0; nf < 2; ++nf)
            acc[i][nf] = __builtin_amdgcn_mfma_f32_16x16x32_bf16(afr[i], bfr[nf], acc[i][nf], 0, 0, 0);
      }
    }
  }
  // store y NHWC bf16: C-frag row=(lane>>4)*4+j (pixel), col=lane&15 (co)
  const int r4 = lk * 4;
#pragma unroll
  for (int i = 0; i < 3; ++i) {
#pragma unroll
    for (int nf = 0; nf < 2; ++nf) {
      int co = (nh * 2 + nf) * 16 + l15;
#pragma unroll
      for (int j = 0; j < 4; ++j) {
        int w = w0 + (mh * 3 + i) * 16 + r4 + j;
        if (w < WID)
          y[((size_t)(b * HW) + h * WID + w) * 64 + co] = f2bf(acc[i][nf][j]);
      }
    }
  }
}

// ---------------- K2: BN partial stats over NHWC bf16 y ----------------
__global__ void k_stats2(const unsigned short* __restrict__ y, float* __restrict__ part) {
  const int t = threadIdx.x;
  const int c2 = (t & 31) * 2;
  const int g = t >> 5;
  float s0 = 0.f, s1 = 0.f, ss0 = 0.f, ss1 = 0.f;
  for (int r = blockIdx.x * 8 + g; r < 4 * HW; r += 256 * 8) {
    unsigned int v = *(const unsigned int*)(y + (size_t)r * 64 + c2);
    float f0 = bf2f((unsigned short)(v & 0xffffu));
    float f1 = bf2f((unsigned short)(v >> 16));
    s0 += f0; ss0 = fmaf(f0, f0, ss0);
    s1 += f1; ss1 = fmaf(f1, f1, ss1);
  }
  __shared__ float ls[8][64], lss[8][64];
  ls[g][c2] = s0; ls[g][c2 + 1] = s1;
  lss[g][c2] = ss0; lss[g][c2 + 1] = ss1;
  __syncthreads();
  if (t < 64) {
    float s = 0.f, ss = 0.f;
    for (int k = 0; k < 8; ++k) { s += ls[k][t]; ss += lss[k][t]; }
    part[(blockIdx.x * 64 + t) * 2] = s;
    part[(blockIdx.x * 64 + t) * 2 + 1] = ss;
  }
}

// ---------------- K2b: final BN scale/shift ----------------
__global__ void k_bnparams(const float* __restrict__ part, const float* __restrict__ gamma,
                           const float* __restrict__ beta, float* __restrict__ ab) {
  const int t = threadIdx.x; // 64
  float s = 0.f, ss = 0.f;
  for (int k = 0; k < 256; ++k) { s += part[(k * 64 + t) * 2]; ss += part[(k * 64 + t) * 2 + 1]; }
  float mu = s / 129600.f;
  float var = ss / 129600.f - mu * mu;
  float a = rsqrtf(var + 1e-5f) * gamma[t];
  ab[t * 2] = a; ab[t * 2 + 1] = beta[t] - mu * a;
}

// ---------------- K3: BN apply + ReLU (elementwise NHWC) ----------------
__global__ void k_bn2(const unsigned short* __restrict__ y, const float* __restrict__ ab,
                      unsigned short* __restrict__ bev) {
  __shared__ float sa[64], sb[64];
  const int t = threadIdx.x;
  if (t < 64) { sa[t] = ab[t * 2]; sb[t] = ab[t * 2 + 1]; }
  __syncthreads();
  size_t id = (size_t)blockIdx.x * 256 + t;
  if (id >= (size_t)4 * HW * 8) return;
  int c0 = (int)(id & 7) * 8;
  u16x8 v = *(const u16x8*)(y + id * 8);
  u16x8 o;
#pragma unroll
  for (int k = 0; k < 8; ++k) {
    float f = fmaf(bf2f(v[k]), sa[c0 + k], sb[c0 + k]);
    o[k] = f2bf(f > 0.f ? f : 0.f);
  }
  *(u16x8*)(bev + id * 8) = o;
}

// ---------------- K4: bilinear sample, wave-per-point, lane=channel ----------------
__global__ void k_points(const float* __restrict__ pts, const unsigned short* __restrict__ bev,
                         unsigned short* __restrict__ pf, int* __restrict__ seg) {
  const int gid = blockIdx.x * blockDim.x + threadIdx.x;
  const int lane = gid & 63;
  const int wid = gid >> 6;
  const int nw = (gridDim.x * blockDim.x) >> 6;
  for (int p = wid; p < NPTS; p += nw) {
    const float* pr = pts + (size_t)p * 9;
    float pbf = pr[0], xx = pr[1], yy = pr[2];
    float swf = pr[6], insf = pr[7];
    int b = (int)pbf;
    float px = (xx - (-54.0f)) / 0.6f;
    float py = (yy - (-54.0f)) / 0.6f;
    int x0 = (int)floorf(px); x0 = min(max(x0, 0), WID - 1);
    int x1 = min(x0 + 1, WID - 1);
    int y0 = (int)floorf(py); y0 = min(max(y0, 0), WID - 1);
    int y1 = min(y0 + 1, WID - 1);
    float x0f = (float)x0, x1f = (float)x1, y0f = (float)y0, y1f = (float)y1;
    float wa = (x1f - px) * (y1f - py);
    float wb = (x1f - px) * (py - y0f);
    float wc = (px - x0f) * (y1f - py);
    float wd = (px - x0f) * (py - y0f);
    float Ia = bf2f(bev[(size_t)((b * WID + y0) * WID + x0) * 64 + lane]);
    float Ib = bf2f(bev[(size_t)((b * WID + y1) * WID + x0) * 64 + lane]);
    float Ic = bf2f(bev[(size_t)((b * WID + y0) * WID + x1) * 64 + lane]);
    float Id = bf2f(bev[(size_t)((b * WID + y1) * WID + x1) * 64 + lane]);
    float f = wa * Ia + wb * Ib + wc * Ic + wd * Id;
    pf[(size_t)p * 64 + lane] = f2bf(f);
    if (lane == 0) seg[p] = (b * 64 + (int)insf) * 10 + (int)swf;
  }
}

// ---------------- K4b: point heads (cls/offset/embedding) ----------------
__global__ void k_heads(const unsigned short* __restrict__ pf,
                        const float* __restrict__ wseg, const float* __restrict__ bseg,
                        const float* __restrict__ wreg, const float* __restrict__ breg,
                        const float* __restrict__ wemb, const float* __restrict__ bemb,
                        float* __restrict__ ocls, float* __restrict__ ooff, float* __restrict__ oemb) {
  const int p = blockIdx.x * 256 + threadIdx.x;
  if (p >= NPTS) return;
  float a0 = bseg[0], a1 = bseg[1], a2 = bseg[2];
  float r0 = breg[0], r1 = breg[1], r2 = breg[2];
  float e0 = bemb[0], e1 = bemb[1];
  const u16x8* q = (const u16x8*)(pf + (size_t)p * 64);
#pragma unroll
  for (int g = 0; g < 8; ++g) {
    u16x8 v8 = q[g];
#pragma unroll
    for (int k = 0; k < 8; ++k) {
      int kk = g * 8 + k;
      float v = bf2f(v8[k]);
      a0 = fmaf(v, wseg[kk * 3 + 0], a0);
      a1 = fmaf(v, wseg[kk * 3 + 1], a1);
      a2 = fmaf(v, wseg[kk * 3 + 2], a2);
      r0 = fmaf(v, wreg[kk * 3 + 0], r0);
      r1 = fmaf(v, wreg[kk * 3 + 1], r1);
      r2 = fmaf(v, wreg[kk * 3 + 2], r2);
      e0 = fmaf(v, wemb[kk * 2 + 0], e0);
      e1 = fmaf(v, wemb[kk * 2 + 1], e1);
    }
  }
  ocls[p * 3 + 0] = a0; ocls[p * 3 + 1] = a1; ocls[p * 3 + 2] = a2;
  ooff[p * 3 + 0] = r0; ooff[p * 3 + 1] = r1; ooff[p * 3 + 2] = r2;
  oemb[p * 2 + 0] = e0; oemb[p * 2 + 1] = e1;
}

// ---------------- K5/K6/K7: counting sort by segment ----------------
__global__ void k_hist(const int* __restrict__ seg, int* __restrict__ cnt) {
  const int p = blockIdx.x * 256 + threadIdx.x;
  if (p < NPTS) atomicAdd(&cnt[seg[p]], 1);
}

__global__ void k_scan(const int* __restrict__ cnt, int* __restrict__ base, int* __restrict__ cursor) {
  __shared__ int csum[256];
  const int t = threadIdx.x;
  int loc[10]; int run = 0;
#pragma unroll
  for (int k = 0; k < 10; ++k) { loc[k] = cnt[t * 10 + k]; run += loc[k]; }
  csum[t] = run;
  __syncthreads();
  if (t == 0) {
    int acc = 0;
    for (int i = 0; i < 256; ++i) { int v = csum[i]; csum[i] = acc; acc += v; }
  }
  __syncthreads();
  int acc = csum[t];
#pragma unroll
  for (int k = 0; k < 10; ++k) {
    int idx = t * 10 + k;
    base[idx] = acc; cursor[idx] = acc;
    acc += loc[k];
  }
}

__global__ void k_scatter(const int* __restrict__ seg, int* __restrict__ cursor, int* __restrict__ order) {
  const int p = blockIdx.x * 256 + threadIdx.x;
  if (p < NPTS) {
    int pos = atomicAdd(&cursor[seg[p]], 1);
    order[pos] = p;
  }
}

// ---------------- K8: per-segment centroid + shape_enc max + feat max ----------------
__global__ void k_seg(const int* __restrict__ cnt, const int* __restrict__ base,
                      const int* __restrict__ order, const float* __restrict__ pts,
                      const unsigned short* __restrict__ pf,
                      const float* __restrict__ wsh, const float* __restrict__ bsh,
                      float* __restrict__ lf, float* __restrict__ centroid,
                      int* __restrict__ nonempty) {
  const int s = blockIdx.x;
  const int t = threadIdx.x; // 64 threads
  const int n = cnt[s];
  const int bs = base[s];
  float sx = 0.f, sy = 0.f, sz = 0.f;
  for (int i = t; i < n; i += 64) {
    int p = order[bs + i];
    const float* pr = pts + (size_t)p * 9;
    sx += pr[1]; sy += pr[2]; sz += pr[3];
  }
#pragma unroll
  for (int m = 32; m > 0; m >>= 1) {
    sx += __shfl_xor(sx, m); sy += __shfl_xor(sy, m); sz += __shfl_xor(sz, m);
  }
  float dn = (float)max(n, 1);
  float cx = sx / dn, cy = sy / dn, cz = sz / dn;
  float w0 = wsh[t], w1 = wsh[64 + t], w2 = wsh[128 + t], bb = bsh[t];
  float smax = -INFINITY, lmax = -INFINITY;
  for (int i = 0; i < n; ++i) {
    int p = order[bs + i];
    const float* pr = pts + (size_t)p * 9;
    float c0 = pr[1] - cx, c1 = pr[2] - cy, c2 = pr[3] - cz;
    float sv = fmaf(c0, w0, fmaf(c1, w1, fmaf(c2, w2, bb)));
    smax = fmaxf(smax, sv);
    lmax = fmaxf(lmax, bf2f(pf[(size_t)p * 64 + t]));
  }
  bool ne = n > 0;
  lf[s * 64 + t] = (ne ? lmax : 0.f) + (ne ? smax : 0.f);
  if (t == 0) {
    nonempty[s] = ne ? 1 : 0;
    centroid[s * 3 + 0] = cx; centroid[s * 3 + 1] = cy; centroid[s * 3 + 2] = cz;
  }
}

// ---------------- K9: per-instance globals + sweep min/max + inst_mos ----------------
__global__ void k_glob(const float* __restrict__ lf, const int* __restrict__ ne,
                       const float* __restrict__ centroid,
                       const float* __restrict__ wmos, const float* __restrict__ bmos,
                       float* __restrict__ gf, float* __restrict__ tc, float* __restrict__ ic,
                       float* __restrict__ omos) {
  const int i = blockIdx.x;
  const int t = threadIdx.x; // 64 threads
  float g = -INFINITY;
  int maxsw = -1, minsw = 10;
  bool any = false;
#pragma unroll
  for (int s = 0; s < 10; ++s) {
    int idx = i * 10 + s;
    bool e = ne[idx] != 0;
    float v = lf[idx * 64 + t];
    g = fmaxf(g, e ? v : -INFINITY);
    if (e) { any = true; maxsw = s; minsw = min(minsw, s); }
  }
  float gv = any ? g : 0.f;
  gf[i * 64 + t] = gv;
  int idxmax = min(max(i * 10 + maxsw, 0), NSEG - 1);
  int idxmin = min(max(i * 10 + minsw, 0), NSEG - 1);
  float tcx = centroid[idxmax * 3 + 0], tcy = centroid[idxmax * 3 + 1], tcz = centroid[idxmax * 3 + 2];
  float icx = centroid[idxmin * 3 + 0], icy = centroid[idxmin * 3 + 1], icz = centroid[idxmin * 3 + 2];
  if (t == 0) {
    tc[i * 3 + 0] = tcx; tc[i * 3 + 1] = tcy; tc[i * 3 + 2] = tcz;
    ic[i * 3 + 0] = icx; ic[i * 3 + 1] = icy; ic[i * 3 + 2] = icz;
  }
  float r = gv * wmos[t];
#pragma unroll
  for (int m = 32; m > 0; m >>= 1) r += __shfl_xor(r, m);
  if (t == 0) {
    r += icx * wmos[64] + icy * wmos[65] + icz * wmos[66];
    r += tcx * wmos[67] + tcy * wmos[68] + tcz * wmos[69];
    omos[i] = r + bmos[0];
  }
}

// ---------------- K10: locals_tf = locals_cat(134) @ w_tf(134x7) ----------------
__global__ void k_tf(const float* __restrict__ lf, const float* __restrict__ gf,
                     const float* __restrict__ centroid, const float* __restrict__ tc,
                     const float* __restrict__ wtf, const float* __restrict__ btf,
                     float* __restrict__ otf) {
  const int r = blockIdx.x * 256 + threadIdx.x;
  if (r >= NSEG) return;
  const int i = r / 10;
  float acc[7];
#pragma unroll
  for (int j = 0; j < 7; ++j) acc[j] = btf[j];
  for (int k = 0; k < 64; ++k) {
    float v = lf[r * 64 + k];
#pragma unroll
    for (int j = 0; j < 7; ++j) acc[j] = fmaf(v, wtf[k * 7 + j], acc[j]);
  }
  for (int k = 0; k < 64; ++k) {
    float v = gf[i * 64 + k];
#pragma unroll
    for (int j = 0; j < 7; ++j) acc[j] = fmaf(v, wtf[(64 + k) * 7 + j], acc[j]);
  }
#pragma unroll
  for (int c = 0; c < 3; ++c) {
    float v = centroid[r * 3 + c];
#pragma unroll
    for (int j = 0; j < 7; ++j) acc[j] = fmaf(v, wtf[(128 + c) * 7 + j], acc[j]);
  }
#pragma unroll
  for (int c = 0; c < 3; ++c) {
    float v = tc[i * 3 + c];
#pragma unroll
    for (int j = 0; j < 7; ++j) acc[j] = fmaf(v, wtf[(131 + c) * 7 + j], acc[j]);
  }
#pragma unroll
  for (int j = 0; j < 7; ++j) otf[r * 7 + j] = acc[j];
}

extern "C" void kernel_launch(void* const* d_in, const int* in_sizes, int n_in,
                              void* d_out, int out_size, void* d_ws, size_t ws_size,
                              hipStream_t stream) {
  const float* pts   = (const float*)d_in[0];
  const float* x     = (const float*)d_in[1];
  const float* convw = (const float*)d_in[2];
  const float* gamma = (const float*)d_in[3];
  const float* beta  = (const float*)d_in[4];
  const float* wseg  = (const float*)d_in[5];
  const float* bseg  = (const float*)d_in[6];
  const float* wreg  = (const float*)d_in[7];
  const float* breg  = (const float*)d_in[8];
  const float* wemb  = (const float*)d_in[9];
  const float* bemb  = (const float*)d_in[10];
  const float* wsh   = (const float*)d_in[11];
  const float* bsh   = (const float*)d_in[12];
  const float* wtf   = (const float*)d_in[13];
  const float* btf   = (const float*)d_in[14];
  const float* wmos  = (const float*)d_in[15];
  const float* bmos  = (const float*)d_in[16];

  float* out = (float*)d_out;
  float* o_cls = out;                 // 400000 x 3
  float* o_off = out + 1200000;       // 400000 x 3
  float* o_emb = out + 2400000;       // 400000 x 2
  float* o_tf  = out + 3200000;       // 2560 x 7
  float* o_mos = out + 3217920;       // 256 x 1

  char* wsp = (char*)d_ws;
  size_t off = 0;
  auto alloc = [&](size_t bytes) -> void* {
    void* p = wsp + off;
    off = (off + bytes + 255) & ~(size_t)255;
    return p;
  };
  // xt dead after conv; pf (51.2MB) aliases it (66.4MB).
  unsigned short* xt   = (unsigned short*)alloc((size_t)4 * WID * WID * NCI * 2); // 66.4 MB
  unsigned short* pf   = xt;
  unsigned short* wbuf = (unsigned short*)alloc((size_t)9 * 64 * 256 * 2);
  unsigned short* y    = (unsigned short*)alloc((size_t)4 * HW * 64 * 2);         // 16.6 MB
  unsigned short* bev  = (unsigned short*)alloc((size_t)4 * HW * 64 * 2);         // 16.6 MB
  int*   seg      = (int*)alloc((size_t)NPTS * 4);
  int*   order    = (int*)alloc((size_t)NPTS * 4);
  int*   cnt      = (int*)alloc(NSEG * 4);
  int*   base     = (int*)alloc(NSEG * 4);
  int*   cursor   = (int*)alloc(NSEG * 4);
  float* part     = (float*)alloc(256 * 64 * 2 * 4);
  float* ab       = (float*)alloc(64 * 2 * 4);
  float* centroid = (float*)alloc(NSEG * 3 * 4);
  float* lf       = (float*)alloc(NSEG * 64 * 4);
  int*   nonem    = (int*)alloc(NSEG * 4);
  float* gf       = (float*)alloc(NINST * 64 * 4);
  float* tc       = (float*)alloc(NINST * 3 * 4);
  float* ic       = (float*)alloc(NINST * 3 * 4);
  (void)ws_size; (void)n_in; (void)in_sizes; (void)out_size;

  hipMemsetAsync(cnt, 0, NSEG * 4, stream);

  k_transpose<<<dim3(12, WID, 4), 256, 0, stream>>>(x, xt);
  k_wreorg<<<576, 256, 0, stream>>>(convw, wbuf);
  k_conv_mfma<<<dim3(WID, 2, 4), 256, 0, stream>>>(xt, wbuf, y);
  k_stats2<<<256, 256, 0, stream>>>(y, part);
  k_bnparams<<<1, 64, 0, stream>>>(part, gamma, beta, ab);
  k_bn2<<<(4 * HW * 8 + 255) / 256, 256, 0, stream>>>(y, ab, bev);
  k_points<<<1024, 256, 0, stream>>>(pts, bev, pf, seg);
  k_heads<<<(NPTS + 255) / 256, 256, 0, stream>>>(pf, wseg, bseg, wreg, breg, wemb, bemb,
                                                  o_cls, o_off, o_emb);
  k_hist<<<(NPTS + 255) / 256, 256, 0, stream>>>(seg, cnt);
  k_scan<<<1, 256, 0, stream>>>(cnt, base, cursor);
  k_scatter<<<(NPTS + 255) / 256, 256, 0, stream>>>(seg, cursor, order);
  k_seg<<<NSEG, 64, 0, stream>>>(cnt, base, order, pts, pf, wsh, bsh, lf, centroid, nonem);
  k_glob<<<NINST, 64, 0, stream>>>(lf, nonem, centroid, wmos, bmos, gf, tc, ic, o_mos);
  k_tf<<<(NSEG + 255) / 256, 256, 0, stream>>>(lf, gf, centroid, tc, wtf, btf, o_tf);
}

// Round 3
// 507.943 us; speedup vs baseline: 3.7823x; 1.0642x over previous
//
#include <hip/hip_runtime.h>

typedef __attribute__((ext_vector_type(8))) unsigned short u16x8;
typedef __attribute__((ext_vector_type(8))) short s16x8;
typedef __attribute__((ext_vector_type(4))) float f32x4;

#define NPTS 400000
#define HW 32400
#define WID 180
#define NCI 256
#define NCO 64
#define NSEG 2560
#define NINST 256

__device__ __forceinline__ float bf2f(unsigned short u) {
  union { unsigned int i; float f; } v; v.i = ((unsigned int)u) << 16; return v.f;
}
__device__ __forceinline__ unsigned short f2bf(float f) {
  unsigned int u = __float_as_uint(f);
  return (unsigned short)((u + 0x7fffu + ((u >> 16) & 1u)) >> 16);
}

__device__ __forceinline__ void gld_lds16(const void* g, void* l) {
  __builtin_amdgcn_global_load_lds((const __attribute__((address_space(1))) void*)g,
                                   (__attribute__((address_space(3))) void*)l, 16, 0, 0);
}

// ---------------- K0: NCHW fp32 -> NHWC bf16 transpose ----------------
__global__ __launch_bounds__(256) void k_transpose(const float* __restrict__ x,
                                                   unsigned short* __restrict__ xt) {
  const int bw = blockIdx.x;            // 0..11: wtile = bw>>2, citile = bw&3
  const int h = blockIdx.y, b = blockIdx.z;
  const int w0 = (bw >> 2) * 64, ci0 = (bw & 3) * 64;
  __shared__ float tile[64][66];
  const int tid = threadIdx.x;
  const int tx = tid & 63, ty = tid >> 6;
  for (int cc = 0; cc < 16; ++cc) {
    int cl = cc * 4 + ty;
    float v = 0.f;
    int w = w0 + tx;
    if (w < WID) v = x[((size_t)(b * NCI + ci0 + cl) * WID + h) * WID + w];
    tile[tx][cl] = v;
  }
  __syncthreads();
  const int tx2 = tid & 31, ty2 = tid >> 5;
  for (int pp = 0; pp < 8; ++pp) {
    int wl = pp * 8 + ty2;
    int w = w0 + wl;
    if (w >= WID) continue;
    float f0 = tile[wl][2 * tx2], f1 = tile[wl][2 * tx2 + 1];
    unsigned int packed = (unsigned int)f2bf(f0) | ((unsigned int)f2bf(f1) << 16);
    *(unsigned int*)(xt + ((size_t)((b * WID + h) * WID + w)) * NCI + ci0 + 2 * tx2) = packed;
  }
}

// ---------------- K0b: conv_w [64][256][3][3] f32 -> wb[tap][co][ci] bf16 ----------------
__global__ void k_wreorg(const float* __restrict__ wt, unsigned short* __restrict__ wb) {
  int id = blockIdx.x * 256 + threadIdx.x;
  if (id >= 9 * 64 * 256) return;
  int ci = id & 255, co = (id >> 8) & 63, tap = id >> 14;
  wb[id] = f2bf(wt[((size_t)co * 256 + ci) * 9 + tap]);
}

// ---------------- K1: implicit-GEMM conv, double-buffered global_load_lds ----------------
// grid: 1440 1D, XCD-swizzled so each XCD owns one (b,wth) slab of 180 h rows.
// LDS: 2 buffers x 3 rows x 104 px x 128B, XOR-swizzled via pre-swizzled source.
#define RSTRIDE (104 * 128)
__global__ __launch_bounds__(256) void k_conv_mfma(const unsigned short* __restrict__ xt,
                                                   const unsigned short* __restrict__ wb,
                                                   const float* __restrict__ zbuf,
                                                   unsigned short* __restrict__ y) {
  const int wg = blockIdx.x;                    // 0..1439
  const int lin = (wg & 7) * 180 + (wg >> 3);   // bijective: 1440 = 8*180
  const int h = lin % 180;
  const int t2 = lin / 180;                     // b*2 + wth
  const int wth = t2 & 1, b = t2 >> 1;
  const int w0 = wth * 96;
  __shared__ unsigned char strip[2][3 * RSTRIDE];
  const int tid = threadIdx.x;
  const int lane = tid & 63, wv = tid >> 6;
  const int mh = wv >> 1, nh = wv & 1;
  const int l15 = lane & 15, lk = lane >> 4;
  const int l3 = lane >> 3, l7 = lane & 7;

  // precompute per-lane swizzled global sources (chunk 0); chunk advances +128B
  const char* srcs[10];
#pragma unroll
  for (int k = 0; k < 10; ++k) {
    int j = wv + k * 4;
    int row = j / 13, grp = j - row * 13;
    int hh = h + row - 1;
    int w_px = grp * 8 + l3;
    int worig = w0 + w_px - 1;
    bool valid = (j < 39) && (hh >= 0) && (hh < WID) && (worig >= 0) && (worig < WID);
    int sl = l7 ^ (w_px & 7);
    srcs[k] = valid
        ? (const char*)(xt + ((size_t)((b * WID + hh) * WID + worig)) * NCI + sl * 8)
        : (const char*)zbuf + lane * 16;  // 2KB zeros; +chunk*128 stays inside
  }

  f32x4 acc[3][2];
#pragma unroll
  for (int i = 0; i < 3; ++i)
#pragma unroll
    for (int j = 0; j < 2; ++j) { acc[i][j][0] = 0.f; acc[i][j][1] = 0.f; acc[i][j][2] = 0.f; acc[i][j][3] = 0.f; }

  auto stage = [&](unsigned char* buf, int chunk) {
#pragma unroll
    for (int k = 0; k < 10; ++k) {
      int j = wv + k * 4;
      if (j >= 39) break;                 // wave-uniform (only wv=3,k=9)
      int row = j / 13, grp = j - row * 13;
      gld_lds16(srcs[k] + chunk * 128, buf + row * RSTRIDE + grp * 1024);
    }
  };

  stage(strip[0], 0);
  asm volatile("s_waitcnt vmcnt(0)" ::: "memory");
  __syncthreads();

  for (int chunk = 0; chunk < 4; ++chunk) {
    if (chunk < 3) stage(strip[(chunk + 1) & 1], chunk + 1);
    const unsigned char* buf = strip[chunk & 1];
    for (int tap = 0; tap < 9; ++tap) {
      const int dh = tap / 3, dw = tap % 3;
      const unsigned short* wbase = wb + (size_t)tap * (64 * 256) + chunk * 64;
#pragma unroll
      for (int kk = 0; kk < 2; ++kk) {
        s16x8 bfr[2];
#pragma unroll
        for (int nf = 0; nf < 2; ++nf) {
          int co = (nh * 2 + nf) * 16 + l15;
          bfr[nf] = *(const s16x8*)(wbase + (size_t)co * 256 + kk * 32 + lk * 8);
        }
        s16x8 afr[3];
#pragma unroll
        for (int i = 0; i < 3; ++i) {
          int wp = (mh * 3 + i) * 16 + l15 + dw;
          int byte = dh * RSTRIDE + wp * 128 + ((kk * 64 + lk * 16) ^ ((wp & 7) << 4));
          afr[i] = *(const s16x8*)(buf + byte);
        }
#pragma unroll
        for (int i = 0; i < 3; ++i)
#pragma unroll
          for (int nf = 0; nf < 2; ++nf)
            acc[i][nf] = __builtin_amdgcn_mfma_f32_16x16x32_bf16(afr[i], bfr[nf], acc[i][nf], 0, 0, 0);
      }
    }
    asm volatile("s_waitcnt vmcnt(0)" ::: "memory");
    __syncthreads();
  }

  const int r4 = lk * 4;
#pragma unroll
  for (int i = 0; i < 3; ++i) {
#pragma unroll
    for (int nf = 0; nf < 2; ++nf) {
      int co = (nh * 2 + nf) * 16 + l15;
#pragma unroll
      for (int j = 0; j < 4; ++j) {
        int w = w0 + (mh * 3 + i) * 16 + r4 + j;
        if (w < WID)
          y[((size_t)(b * HW) + h * WID + w) * 64 + co] = f2bf(acc[i][nf][j]);
      }
    }
  }
}

// ---------------- K2: BN partial stats over NHWC bf16 y ----------------
__global__ void k_stats2(const unsigned short* __restrict__ y, float* __restrict__ part) {
  const int t = threadIdx.x;
  const int c2 = (t & 31) * 2;
  const int g = t >> 5;
  float s0 = 0.f, s1 = 0.f, ss0 = 0.f, ss1 = 0.f;
  for (int r = blockIdx.x * 8 + g; r < 4 * HW; r += 256 * 8) {
    unsigned int v = *(const unsigned int*)(y + (size_t)r * 64 + c2);
    float f0 = bf2f((unsigned short)(v & 0xffffu));
    float f1 = bf2f((unsigned short)(v >> 16));
    s0 += f0; ss0 = fmaf(f0, f0, ss0);
    s1 += f1; ss1 = fmaf(f1, f1, ss1);
  }
  __shared__ float ls[8][64], lss[8][64];
  ls[g][c2] = s0; ls[g][c2 + 1] = s1;
  lss[g][c2] = ss0; lss[g][c2 + 1] = ss1;
  __syncthreads();
  if (t < 64) {
    float s = 0.f, ss = 0.f;
    for (int k = 0; k < 8; ++k) { s += ls[k][t]; ss += lss[k][t]; }
    part[(blockIdx.x * 64 + t) * 2] = s;
    part[(blockIdx.x * 64 + t) * 2 + 1] = ss;
  }
}

// ---------------- K2b: final BN scale/shift ----------------
__global__ void k_bnparams(const float* __restrict__ part, const float* __restrict__ gamma,
                           const float* __restrict__ beta, float* __restrict__ ab) {
  const int t = threadIdx.x; // 64
  float s = 0.f, ss = 0.f;
  for (int k = 0; k < 256; ++k) { s += part[(k * 64 + t) * 2]; ss += part[(k * 64 + t) * 2 + 1]; }
  float mu = s / 129600.f;
  float var = ss / 129600.f - mu * mu;
  float a = rsqrtf(var + 1e-5f) * gamma[t];
  ab[t * 2] = a; ab[t * 2 + 1] = beta[t] - mu * a;
}

// ---------------- K3: BN apply + ReLU (elementwise NHWC) ----------------
__global__ void k_bn2(const unsigned short* __restrict__ y, const float* __restrict__ ab,
                      unsigned short* __restrict__ bev) {
  __shared__ float sa[64], sb[64];
  const int t = threadIdx.x;
  if (t < 64) { sa[t] = ab[t * 2]; sb[t] = ab[t * 2 + 1]; }
  __syncthreads();
  size_t id = (size_t)blockIdx.x * 256 + t;
  if (id >= (size_t)4 * HW * 8) return;
  int c0 = (int)(id & 7) * 8;
  u16x8 v = *(const u16x8*)(y + id * 8);
  u16x8 o;
#pragma unroll
  for (int k = 0; k < 8; ++k) {
    float f = fmaf(bf2f(v[k]), sa[c0 + k], sb[c0 + k]);
    o[k] = f2bf(f > 0.f ? f : 0.f);
  }
  *(u16x8*)(bev + id * 8) = o;
}

// ---------------- K4: bilinear sample + fused histogram ----------------
__global__ void k_points(const float* __restrict__ pts, const unsigned short* __restrict__ bev,
                         unsigned short* __restrict__ pf, int* __restrict__ seg,
                         int* __restrict__ rankp, int* __restrict__ cnt) {
  const int gid = blockIdx.x * blockDim.x + threadIdx.x;
  const int lane = gid & 63;
  const int wid = gid >> 6;
  const int nw = (gridDim.x * blockDim.x) >> 6;
  for (int p = wid; p < NPTS; p += nw) {
    const float* pr = pts + (size_t)p * 9;
    float pbf = pr[0], xx = pr[1], yy = pr[2];
    float swf = pr[6], insf = pr[7];
    int b = (int)pbf;
    float px = (xx - (-54.0f)) / 0.6f;
    float py = (yy - (-54.0f)) / 0.6f;
    int x0 = (int)floorf(px); x0 = min(max(x0, 0), WID - 1);
    int x1 = min(x0 + 1, WID - 1);
    int y0 = (int)floorf(py); y0 = min(max(y0, 0), WID - 1);
    int y1 = min(y0 + 1, WID - 1);
    float x0f = (float)x0, x1f = (float)x1, y0f = (float)y0, y1f = (float)y1;
    float wa = (x1f - px) * (y1f - py);
    float wb = (x1f - px) * (py - y0f);
    float wc = (px - x0f) * (y1f - py);
    float wd = (px - x0f) * (py - y0f);
    float Ia = bf2f(bev[(size_t)((b * WID + y0) * WID + x0) * 64 + lane]);
    float Ib = bf2f(bev[(size_t)((b * WID + y1) * WID + x0) * 64 + lane]);
    float Ic = bf2f(bev[(size_t)((b * WID + y0) * WID + x1) * 64 + lane]);
    float Id = bf2f(bev[(size_t)((b * WID + y1) * WID + x1) * 64 + lane]);
    float f = wa * Ia + wb * Ib + wc * Ic + wd * Id;
    pf[(size_t)p * 64 + lane] = f2bf(f);
    if (lane == 0) {
      int s = (b * 64 + (int)insf) * 10 + (int)swf;
      seg[p] = s;
      rankp[p] = atomicAdd(&cnt[s], 1);
    }
  }
}

// ---------------- K4b: point heads (cls/offset/embedding) ----------------
__global__ void k_heads(const unsigned short* __restrict__ pf,
                        const float* __restrict__ wseg, const float* __restrict__ bseg,
                        const float* __restrict__ wreg, const float* __restrict__ breg,
                        const float* __restrict__ wemb, const float* __restrict__ bemb,
                        float* __restrict__ ocls, float* __restrict__ ooff, float* __restrict__ oemb) {
  const int p = blockIdx.x * 256 + threadIdx.x;
  if (p >= NPTS) return;
  float a0 = bseg[0], a1 = bseg[1], a2 = bseg[2];
  float r0 = breg[0], r1 = breg[1], r2 = breg[2];
  float e0 = bemb[0], e1 = bemb[1];
  const u16x8* q = (const u16x8*)(pf + (size_t)p * 64);
#pragma unroll
  for (int g = 0; g < 8; ++g) {
    u16x8 v8 = q[g];
#pragma unroll
    for (int k = 0; k < 8; ++k) {
      int kk = g * 8 + k;
      float v = bf2f(v8[k]);
      a0 = fmaf(v, wseg[kk * 3 + 0], a0);
      a1 = fmaf(v, wseg[kk * 3 + 1], a1);
      a2 = fmaf(v, wseg[kk * 3 + 2], a2);
      r0 = fmaf(v, wreg[kk * 3 + 0], r0);
      r1 = fmaf(v, wreg[kk * 3 + 1], r1);
      r2 = fmaf(v, wreg[kk * 3 + 2], r2);
      e0 = fmaf(v, wemb[kk * 2 + 0], e0);
      e1 = fmaf(v, wemb[kk * 2 + 1], e1);
    }
  }
  ocls[p * 3 + 0] = a0; ocls[p * 3 + 1] = a1; ocls[p * 3 + 2] = a2;
  ooff[p * 3 + 0] = r0; ooff[p * 3 + 1] = r1; ooff[p * 3 + 2] = r2;
  oemb[p * 2 + 0] = e0; oemb[p * 2 + 1] = e1;
}

// ---------------- K6: exclusive scan over 2560 counts ----------------
__global__ void k_scan(const int* __restrict__ cnt, int* __restrict__ base) {
  __shared__ int csum[256];
  const int t = threadIdx.x;
  int loc[10]; int run = 0;
#pragma unroll
  for (int k = 0; k < 10; ++k) { loc[k] = cnt[t * 10 + k]; run += loc[k]; }
  csum[t] = run;
  __syncthreads();
  if (t == 0) {
    int acc = 0;
    for (int i = 0; i < 256; ++i) { int v = csum[i]; csum[i] = acc; acc += v; }
  }
  __syncthreads();
  int acc = csum[t];
#pragma unroll
  for (int k = 0; k < 10; ++k) {
    int idx = t * 10 + k;
    base[idx] = acc;
    acc += loc[k];
  }
}

// ---------------- K7: atomic-free scatter using precomputed ranks ----------------
__global__ void k_scatter(const int* __restrict__ seg, const int* __restrict__ rankp,
                          const int* __restrict__ base, int* __restrict__ order) {
  const int p = blockIdx.x * 256 + threadIdx.x;
  if (p < NPTS) order[base[seg[p]] + rankp[p]] = p;
}

// ---------------- K8: per-segment centroid + shape max + feat max (4 waves) ----------------
__global__ __launch_bounds__(256) void k_seg(const int* __restrict__ cnt, const int* __restrict__ base,
                      const int* __restrict__ order, const float* __restrict__ pts,
                      const unsigned short* __restrict__ pf,
                      const float* __restrict__ wsh, const float* __restrict__ bsh,
                      float* __restrict__ lf, float* __restrict__ centroid,
                      int* __restrict__ nonempty) {
  const int s = blockIdx.x;
  const int t = threadIdx.x, lane = t & 63, wv = t >> 6;
  const int n = cnt[s], bs = base[s];
  float sx = 0.f, sy = 0.f, sz = 0.f;
  for (int i = t; i < n; i += 256) {
    int p = order[bs + i];
    const float* pr = pts + (size_t)p * 9;
    sx += pr[1]; sy += pr[2]; sz += pr[3];
  }
#pragma unroll
  for (int m = 32; m > 0; m >>= 1) {
    sx += __shfl_xor(sx, m); sy += __shfl_xor(sy, m); sz += __shfl_xor(sz, m);
  }
  __shared__ float red[3][4];
  __shared__ float csh[3];
  if (lane == 0) { red[0][wv] = sx; red[1][wv] = sy; red[2][wv] = sz; }
  __syncthreads();
  if (t == 0) {
    float dn = (float)max(n, 1);
    csh[0] = (red[0][0] + red[0][1] + red[0][2] + red[0][3]) / dn;
    csh[1] = (red[1][0] + red[1][1] + red[1][2] + red[1][3]) / dn;
    csh[2] = (red[2][0] + red[2][1] + red[2][2] + red[2][3]) / dn;
  }
  __syncthreads();
  const float cx = csh[0], cy = csh[1], cz = csh[2];
  const float w0 = wsh[lane], w1 = wsh[64 + lane], w2 = wsh[128 + lane], bb = bsh[lane];
  float smax = -INFINITY, lmax = -INFINITY;
  for (int i = wv; i < n; i += 4) {
    int p = order[bs + i];
    const float* pr = pts + (size_t)p * 9;
    float sv = fmaf(pr[1] - cx, w0, fmaf(pr[2] - cy, w1, fmaf(pr[3] - cz, w2, bb)));
    smax = fmaxf(smax, sv);
    lmax = fmaxf(lmax, bf2f(pf[(size_t)p * 64 + lane]));
  }
  __shared__ float rs[4][64], rl[4][64];
  rs[wv][lane] = smax; rl[wv][lane] = lmax;
  __syncthreads();
  if (wv == 0) {
    smax = fmaxf(fmaxf(rs[0][lane], rs[1][lane]), fmaxf(rs[2][lane], rs[3][lane]));
    lmax = fmaxf(fmaxf(rl[0][lane], rl[1][lane]), fmaxf(rl[2][lane], rl[3][lane]));
    bool ne = n > 0;
    lf[s * 64 + lane] = (ne ? lmax : 0.f) + (ne ? smax : 0.f);
    if (lane == 0) {
      nonempty[s] = ne ? 1 : 0;
      centroid[s * 3 + 0] = cx; centroid[s * 3 + 1] = cy; centroid[s * 3 + 2] = cz;
    }
  }
}

// ---------------- K9: per-instance globals + sweep min/max + inst_mos ----------------
__global__ void k_glob(const float* __restrict__ lf, const int* __restrict__ ne,
                       const float* __restrict__ centroid,
                       const float* __restrict__ wmos, const float* __restrict__ bmos,
                       float* __restrict__ gf, float* __restrict__ tc, float* __restrict__ ic,
                       float* __restrict__ omos) {
  const int i = blockIdx.x;
  const int t = threadIdx.x; // 64 threads
  float g = -INFINITY;
  int maxsw = -1, minsw = 10;
  bool any = false;
#pragma unroll
  for (int s = 0; s < 10; ++s) {
    int idx = i * 10 + s;
    bool e = ne[idx] != 0;
    float v = lf[idx * 64 + t];
    g = fmaxf(g, e ? v : -INFINITY);
    if (e) { any = true; maxsw = s; minsw = min(minsw, s); }
  }
  float gv = any ? g : 0.f;
  gf[i * 64 + t] = gv;
  int idxmax = min(max(i * 10 + maxsw, 0), NSEG - 1);
  int idxmin = min(max(i * 10 + minsw, 0), NSEG - 1);
  float tcx = centroid[idxmax * 3 + 0], tcy = centroid[idxmax * 3 + 1], tcz = centroid[idxmax * 3 + 2];
  float icx = centroid[idxmin * 3 + 0], icy = centroid[idxmin * 3 + 1], icz = centroid[idxmin * 3 + 2];
  if (t == 0) {
    tc[i * 3 + 0] = tcx; tc[i * 3 + 1] = tcy; tc[i * 3 + 2] = tcz;
    ic[i * 3 + 0] = icx; ic[i * 3 + 1] = icy; ic[i * 3 + 2] = icz;
  }
  float r = gv * wmos[t];
#pragma unroll
  for (int m = 32; m > 0; m >>= 1) r += __shfl_xor(r, m);
  if (t == 0) {
    r += icx * wmos[64] + icy * wmos[65] + icz * wmos[66];
    r += tcx * wmos[67] + tcy * wmos[68] + tcz * wmos[69];
    omos[i] = r + bmos[0];
  }
}

// ---------------- K10: locals_tf = locals_cat(134) @ w_tf(134x7) ----------------
__global__ void k_tf(const float* __restrict__ lf, const float* __restrict__ gf,
                     const float* __restrict__ centroid, const float* __restrict__ tc,
                     const float* __restrict__ wtf, const float* __restrict__ btf,
                     float* __restrict__ otf) {
  const int r = blockIdx.x * 256 + threadIdx.x;
  if (r >= NSEG) return;
  const int i = r / 10;
  float acc[7];
#pragma unroll
  for (int j = 0; j < 7; ++j) acc[j] = btf[j];
  for (int k = 0; k < 64; ++k) {
    float v = lf[r * 64 + k];
#pragma unroll
    for (int j = 0; j < 7; ++j) acc[j] = fmaf(v, wtf[k * 7 + j], acc[j]);
  }
  for (int k = 0; k < 64; ++k) {
    float v = gf[i * 64 + k];
#pragma unroll
    for (int j = 0; j < 7; ++j) acc[j] = fmaf(v, wtf[(64 + k) * 7 + j], acc[j]);
  }
#pragma unroll
  for (int c = 0; c < 3; ++c) {
    float v = centroid[r * 3 + c];
#pragma unroll
    for (int j = 0; j < 7; ++j) acc[j] = fmaf(v, wtf[(128 + c) * 7 + j], acc[j]);
  }
#pragma unroll
  for (int c = 0; c < 3; ++c) {
    float v = tc[i * 3 + c];
#pragma unroll
    for (int j = 0; j < 7; ++j) acc[j] = fmaf(v, wtf[(131 + c) * 7 + j], acc[j]);
  }
#pragma unroll
  for (int j = 0; j < 7; ++j) otf[r * 7 + j] = acc[j];
}

extern "C" void kernel_launch(void* const* d_in, const int* in_sizes, int n_in,
                              void* d_out, int out_size, void* d_ws, size_t ws_size,
                              hipStream_t stream) {
  const float* pts   = (const float*)d_in[0];
  const float* x     = (const float*)d_in[1];
  const float* convw = (const float*)d_in[2];
  const float* gamma = (const float*)d_in[3];
  const float* beta  = (const float*)d_in[4];
  const float* wseg  = (const float*)d_in[5];
  const float* bseg  = (const float*)d_in[6];
  const float* wreg  = (const float*)d_in[7];
  const float* breg  = (const float*)d_in[8];
  const float* wemb  = (const float*)d_in[9];
  const float* bemb  = (const float*)d_in[10];
  const float* wsh   = (const float*)d_in[11];
  const float* bsh   = (const float*)d_in[12];
  const float* wtf   = (const float*)d_in[13];
  const float* btf   = (const float*)d_in[14];
  const float* wmos  = (const float*)d_in[15];
  const float* bmos  = (const float*)d_in[16];

  float* out = (float*)d_out;
  float* o_cls = out;                 // 400000 x 3
  float* o_off = out + 1200000;       // 400000 x 3
  float* o_emb = out + 2400000;       // 400000 x 2
  float* o_tf  = out + 3200000;       // 2560 x 7
  float* o_mos = out + 3217920;       // 256 x 1

  char* wsp = (char*)d_ws;
  size_t off = 0;
  auto alloc = [&](size_t bytes) -> void* {
    void* p = wsp + off;
    off = (off + bytes + 255) & ~(size_t)255;
    return p;
  };
  // xt dead after conv -> pf aliases it. y dead after bn2 -> rankp aliases it.
  unsigned short* xt   = (unsigned short*)alloc((size_t)4 * WID * WID * NCI * 2); // 66.4 MB
  unsigned short* pf   = xt;
  unsigned short* wbuf = (unsigned short*)alloc((size_t)9 * 64 * 256 * 2);
  unsigned short* y    = (unsigned short*)alloc((size_t)4 * HW * 64 * 2);         // 16.6 MB
  int*            rankp = (int*)y;
  unsigned short* bev  = (unsigned short*)alloc((size_t)4 * HW * 64 * 2);         // 16.6 MB
  int*   seg      = (int*)alloc((size_t)NPTS * 4);
  int*   order    = (int*)alloc((size_t)NPTS * 4);
  int*   cnt      = (int*)alloc(NSEG * 4);
  int*   base     = (int*)alloc(NSEG * 4);
  float* part     = (float*)alloc(256 * 64 * 2 * 4);
  float* ab       = (float*)alloc(64 * 2 * 4);
  float* centroid = (float*)alloc(NSEG * 3 * 4);
  float* lf       = (float*)alloc(NSEG * 64 * 4);
  int*   nonem    = (int*)alloc(NSEG * 4);
  float* gf       = (float*)alloc(NINST * 64 * 4);
  float* tc       = (float*)alloc(NINST * 3 * 4);
  float* ic       = (float*)alloc(NINST * 3 * 4);
  float* zbuf     = (float*)alloc(2048);
  (void)ws_size; (void)n_in; (void)in_sizes; (void)out_size;

  hipMemsetAsync(cnt, 0, NSEG * 4, stream);
  hipMemsetAsync(zbuf, 0, 2048, stream);

  k_transpose<<<dim3(12, WID, 4), 256, 0, stream>>>(x, xt);
  k_wreorg<<<576, 256, 0, stream>>>(convw, wbuf);
  k_conv_mfma<<<1440, 256, 0, stream>>>(xt, wbuf, zbuf, y);
  k_stats2<<<256, 256, 0, stream>>>(y, part);
  k_bnparams<<<1, 64, 0, stream>>>(part, gamma, beta, ab);
  k_bn2<<<(4 * HW * 8 + 255) / 256, 256, 0, stream>>>(y, ab, bev);
  k_points<<<1024, 256, 0, stream>>>(pts, bev, pf, seg, rankp, cnt);
  k_heads<<<(NPTS + 255) / 256, 256, 0, stream>>>(pf, wseg, bseg, wreg, breg, wemb, bemb,
                                                  o_cls, o_off, o_emb);
  k_scan<<<1, 256, 0, stream>>>(cnt, base);
  k_scatter<<<(NPTS + 255) / 256, 256, 0, stream>>>(seg, rankp, base, order);
  k_seg<<<NSEG, 256, 0, stream>>>(cnt, base, order, pts, pf, wsh, bsh, lf, centroid, nonem);
  k_glob<<<NINST, 64, 0, stream>>>(lf, nonem, centroid, wmos, bmos, gf, tc, ic, o_mos);
  k_tf<<<(NSEG + 255) / 256, 256, 0, stream>>>(lf, gf, centroid, tc, wtf, btf, o_tf);
}

// Round 4
// 484.582 us; speedup vs baseline: 3.9646x; 1.0482x over previous
//
#include <hip/hip_runtime.h>

typedef __attribute__((ext_vector_type(8))) unsigned short u16x8;
typedef __attribute__((ext_vector_type(8))) short s16x8;
typedef __attribute__((ext_vector_type(4))) float f32x4;

#define NPTS 400000
#define HW 32400
#define WID 180
#define NCI 256
#define NCO 64
#define NSEG 2560
#define NINST 256

__device__ __forceinline__ float bf2f(unsigned short u) {
  union { unsigned int i; float f; } v; v.i = ((unsigned int)u) << 16; return v.f;
}
__device__ __forceinline__ unsigned short f2bf(float f) {
  unsigned int u = __float_as_uint(f);
  return (unsigned short)((u + 0x7fffu + ((u >> 16) & 1u)) >> 16);
}

__device__ __forceinline__ void gld_lds16(const void* g, void* l) {
  __builtin_amdgcn_global_load_lds((const __attribute__((address_space(1))) void*)g,
                                   (__attribute__((address_space(3))) void*)l, 16, 0, 0);
}

// ---------------- K0: NCHW fp32 -> NHWC bf16 transpose ----------------
__global__ __launch_bounds__(256) void k_transpose(const float* __restrict__ x,
                                                   unsigned short* __restrict__ xt) {
  const int bw = blockIdx.x;            // 0..11: wtile = bw>>2, citile = bw&3
  const int h = blockIdx.y, b = blockIdx.z;
  const int w0 = (bw >> 2) * 64, ci0 = (bw & 3) * 64;
  __shared__ float tile[64][66];
  const int tid = threadIdx.x;
  const int tx = tid & 63, ty = tid >> 6;
  for (int cc = 0; cc < 16; ++cc) {
    int cl = cc * 4 + ty;
    float v = 0.f;
    int w = w0 + tx;
    if (w < WID) v = x[((size_t)(b * NCI + ci0 + cl) * WID + h) * WID + w];
    tile[tx][cl] = v;
  }
  __syncthreads();
  const int tx2 = tid & 31, ty2 = tid >> 5;
  for (int pp = 0; pp < 8; ++pp) {
    int wl = pp * 8 + ty2;
    int w = w0 + wl;
    if (w >= WID) continue;
    float f0 = tile[wl][2 * tx2], f1 = tile[wl][2 * tx2 + 1];
    unsigned int packed = (unsigned int)f2bf(f0) | ((unsigned int)f2bf(f1) << 16);
    *(unsigned int*)(xt + ((size_t)((b * WID + h) * WID + w)) * NCI + ci0 + 2 * tx2) = packed;
  }
}

// ---------------- K0b: conv_w [64][256][3][3] f32 -> wb[tap][co][ci] bf16 ----------------
__global__ void k_wreorg(const float* __restrict__ wt, unsigned short* __restrict__ wb) {
  int id = blockIdx.x * 256 + threadIdx.x;
  if (id >= 9 * 64 * 256) return;
  int ci = id & 255, co = (id >> 8) & 63, tap = id >> 14;
  wb[id] = f2bf(wt[((size_t)co * 256 + ci) * 9 + tap]);
}

// ---------------- K1: implicit-GEMM conv, double-buffered global_load_lds ----------------
#define RSTRIDE (104 * 128)
__global__ __launch_bounds__(256) void k_conv_mfma(const unsigned short* __restrict__ xt,
                                                   const unsigned short* __restrict__ wb,
                                                   const float* __restrict__ zbuf,
                                                   unsigned short* __restrict__ y) {
  const int wg = blockIdx.x;                    // 0..1439
  const int lin = (wg & 7) * 180 + (wg >> 3);   // bijective: 1440 = 8*180
  const int h = lin % 180;
  const int t2 = lin / 180;                     // b*2 + wth
  const int wth = t2 & 1, b = t2 >> 1;
  const int w0 = wth * 96;
  __shared__ unsigned char strip[2][3 * RSTRIDE];
  const int tid = threadIdx.x;
  const int lane = tid & 63, wv = tid >> 6;
  const int mh = wv >> 1, nh = wv & 1;
  const int l15 = lane & 15, lk = lane >> 4;
  const int l3 = lane >> 3, l7 = lane & 7;

  const char* srcs[10];
#pragma unroll
  for (int k = 0; k < 10; ++k) {
    int j = wv + k * 4;
    int row = j / 13, grp = j - row * 13;
    int hh = h + row - 1;
    int w_px = grp * 8 + l3;
    int worig = w0 + w_px - 1;
    bool valid = (j < 39) && (hh >= 0) && (hh < WID) && (worig >= 0) && (worig < WID);
    int sl = l7 ^ (w_px & 7);
    srcs[k] = valid
        ? (const char*)(xt + ((size_t)((b * WID + hh) * WID + worig)) * NCI + sl * 8)
        : (const char*)zbuf + lane * 16;
  }

  f32x4 acc[3][2];
#pragma unroll
  for (int i = 0; i < 3; ++i)
#pragma unroll
    for (int j = 0; j < 2; ++j) { acc[i][j][0] = 0.f; acc[i][j][1] = 0.f; acc[i][j][2] = 0.f; acc[i][j][3] = 0.f; }

  auto stage = [&](unsigned char* buf, int chunk) {
#pragma unroll
    for (int k = 0; k < 10; ++k) {
      int j = wv + k * 4;
      if (j >= 39) break;
      int row = j / 13, grp = j - row * 13;
      gld_lds16(srcs[k] + chunk * 128, buf + row * RSTRIDE + grp * 1024);
    }
  };

  stage(strip[0], 0);
  asm volatile("s_waitcnt vmcnt(0)" ::: "memory");
  __syncthreads();

  for (int chunk = 0; chunk < 4; ++chunk) {
    if (chunk < 3) stage(strip[(chunk + 1) & 1], chunk + 1);
    const unsigned char* buf = strip[chunk & 1];
    for (int tap = 0; tap < 9; ++tap) {
      const int dh = tap / 3, dw = tap % 3;
      const unsigned short* wbase = wb + (size_t)tap * (64 * 256) + chunk * 64;
#pragma unroll
      for (int kk = 0; kk < 2; ++kk) {
        s16x8 bfr[2];
#pragma unroll
        for (int nf = 0; nf < 2; ++nf) {
          int co = (nh * 2 + nf) * 16 + l15;
          bfr[nf] = *(const s16x8*)(wbase + (size_t)co * 256 + kk * 32 + lk * 8);
        }
        s16x8 afr[3];
#pragma unroll
        for (int i = 0; i < 3; ++i) {
          int wp = (mh * 3 + i) * 16 + l15 + dw;
          int byte = dh * RSTRIDE + wp * 128 + ((kk * 64 + lk * 16) ^ ((wp & 7) << 4));
          afr[i] = *(const s16x8*)(buf + byte);
        }
#pragma unroll
        for (int i = 0; i < 3; ++i)
#pragma unroll
          for (int nf = 0; nf < 2; ++nf)
            acc[i][nf] = __builtin_amdgcn_mfma_f32_16x16x32_bf16(afr[i], bfr[nf], acc[i][nf], 0, 0, 0);
      }
    }
    asm volatile("s_waitcnt vmcnt(0)" ::: "memory");
    __syncthreads();
  }

  const int r4 = lk * 4;
#pragma unroll
  for (int i = 0; i < 3; ++i) {
#pragma unroll
    for (int nf = 0; nf < 2; ++nf) {
      int co = (nh * 2 + nf) * 16 + l15;
#pragma unroll
      for (int j = 0; j < 4; ++j) {
        int w = w0 + (mh * 3 + i) * 16 + r4 + j;
        if (w < WID)
          y[((size_t)(b * HW) + h * WID + w) * 64 + co] = f2bf(acc[i][nf][j]);
      }
    }
  }
}

// ---------------- K2: BN partial stats over NHWC bf16 y ----------------
__global__ void k_stats2(const unsigned short* __restrict__ y, float* __restrict__ part) {
  const int t = threadIdx.x;
  const int c2 = (t & 31) * 2;
  const int g = t >> 5;
  float s0 = 0.f, s1 = 0.f, ss0 = 0.f, ss1 = 0.f;
  for (int r = blockIdx.x * 8 + g; r < 4 * HW; r += 256 * 8) {
    unsigned int v = *(const unsigned int*)(y + (size_t)r * 64 + c2);
    float f0 = bf2f((unsigned short)(v & 0xffffu));
    float f1 = bf2f((unsigned short)(v >> 16));
    s0 += f0; ss0 = fmaf(f0, f0, ss0);
    s1 += f1; ss1 = fmaf(f1, f1, ss1);
  }
  __shared__ float ls[8][64], lss[8][64];
  ls[g][c2] = s0; ls[g][c2 + 1] = s1;
  lss[g][c2] = ss0; lss[g][c2 + 1] = ss1;
  __syncthreads();
  if (t < 64) {
    float s = 0.f, ss = 0.f;
    for (int k = 0; k < 8; ++k) { s += ls[k][t]; ss += lss[k][t]; }
    part[(blockIdx.x * 64 + t) * 2] = s;
    part[(blockIdx.x * 64 + t) * 2 + 1] = ss;
  }
}

// ---------------- K2b: final BN scale/shift ----------------
__global__ void k_bnparams(const float* __restrict__ part, const float* __restrict__ gamma,
                           const float* __restrict__ beta, float* __restrict__ ab) {
  const int t = threadIdx.x; // 64
  float s = 0.f, ss = 0.f;
  for (int k = 0; k < 256; ++k) { s += part[(k * 64 + t) * 2]; ss += part[(k * 64 + t) * 2 + 1]; }
  float mu = s / 129600.f;
  float var = ss / 129600.f - mu * mu;
  float a = rsqrtf(var + 1e-5f) * gamma[t];
  ab[t * 2] = a; ab[t * 2 + 1] = beta[t] - mu * a;
}

// ---------------- K3: BN apply + ReLU (elementwise NHWC) ----------------
__global__ void k_bn2(const unsigned short* __restrict__ y, const float* __restrict__ ab,
                      unsigned short* __restrict__ bev) {
  __shared__ float sa[64], sb[64];
  const int t = threadIdx.x;
  if (t < 64) { sa[t] = ab[t * 2]; sb[t] = ab[t * 2 + 1]; }
  __syncthreads();
  size_t id = (size_t)blockIdx.x * 256 + t;
  if (id >= (size_t)4 * HW * 8) return;
  int c0 = (int)(id & 7) * 8;
  u16x8 v = *(const u16x8*)(y + id * 8);
  u16x8 o;
#pragma unroll
  for (int k = 0; k < 8; ++k) {
    float f = fmaf(bf2f(v[k]), sa[c0 + k], sb[c0 + k]);
    o[k] = f2bf(f > 0.f ? f : 0.f);
  }
  *(u16x8*)(bev + id * 8) = o;
}

// ---------------- K4: bilinear sample + fused histogram ----------------
// 4 points per wave, fully unrolled -> 16+ independent loads in flight.
__global__ __launch_bounds__(256) void k_points(const float* __restrict__ pts,
                         const unsigned short* __restrict__ bev,
                         unsigned short* __restrict__ pf, int* __restrict__ seg,
                         int* __restrict__ rankp, int* __restrict__ cnt) {
  const int gid = blockIdx.x * 256 + threadIdx.x;
  const int lane = gid & 63;
  const int wid = gid >> 6;
#pragma unroll
  for (int it = 0; it < 4; ++it) {
    int p = wid * 4 + it;
    if (p >= NPTS) continue;
    const float* pr = pts + (size_t)p * 9;
    float pbf = pr[0], xx = pr[1], yy = pr[2];
    float swf = pr[6], insf = pr[7];
    int b = (int)pbf;
    float px = (xx - (-54.0f)) / 0.6f;
    float py = (yy - (-54.0f)) / 0.6f;
    int x0 = (int)floorf(px); x0 = min(max(x0, 0), WID - 1);
    int x1 = min(x0 + 1, WID - 1);
    int y0 = (int)floorf(py); y0 = min(max(y0, 0), WID - 1);
    int y1 = min(y0 + 1, WID - 1);
    float x0f = (float)x0, x1f = (float)x1, y0f = (float)y0, y1f = (float)y1;
    float wa = (x1f - px) * (y1f - py);
    float wb = (x1f - px) * (py - y0f);
    float wc = (px - x0f) * (y1f - py);
    float wd = (px - x0f) * (py - y0f);
    float Ia = bf2f(bev[(size_t)((b * WID + y0) * WID + x0) * 64 + lane]);
    float Ib = bf2f(bev[(size_t)((b * WID + y1) * WID + x0) * 64 + lane]);
    float Ic = bf2f(bev[(size_t)((b * WID + y0) * WID + x1) * 64 + lane]);
    float Id = bf2f(bev[(size_t)((b * WID + y1) * WID + x1) * 64 + lane]);
    float f = wa * Ia + wb * Ib + wc * Ic + wd * Id;
    pf[(size_t)p * 64 + lane] = f2bf(f);
    if (lane == 0) {
      int s = (b * 64 + (int)insf) * 10 + (int)swf;
      seg[p] = s;
      rankp[p] = atomicAdd(&cnt[s], 1);
    }
  }
}

// ---------------- K4b: point heads (cls/offset/embedding) ----------------
__global__ void k_heads(const unsigned short* __restrict__ pf,
                        const float* __restrict__ wseg, const float* __restrict__ bseg,
                        const float* __restrict__ wreg, const float* __restrict__ breg,
                        const float* __restrict__ wemb, const float* __restrict__ bemb,
                        float* __restrict__ ocls, float* __restrict__ ooff, float* __restrict__ oemb) {
  const int p = blockIdx.x * 256 + threadIdx.x;
  if (p >= NPTS) return;
  float a0 = bseg[0], a1 = bseg[1], a2 = bseg[2];
  float r0 = breg[0], r1 = breg[1], r2 = breg[2];
  float e0 = bemb[0], e1 = bemb[1];
  const u16x8* q = (const u16x8*)(pf + (size_t)p * 64);
#pragma unroll
  for (int g = 0; g < 8; ++g) {
    u16x8 v8 = q[g];
#pragma unroll
    for (int k = 0; k < 8; ++k) {
      int kk = g * 8 + k;
      float v = bf2f(v8[k]);
      a0 = fmaf(v, wseg[kk * 3 + 0], a0);
      a1 = fmaf(v, wseg[kk * 3 + 1], a1);
      a2 = fmaf(v, wseg[kk * 3 + 2], a2);
      r0 = fmaf(v, wreg[kk * 3 + 0], r0);
      r1 = fmaf(v, wreg[kk * 3 + 1], r1);
      r2 = fmaf(v, wreg[kk * 3 + 2], r2);
      e0 = fmaf(v, wemb[kk * 2 + 0], e0);
      e1 = fmaf(v, wemb[kk * 2 + 1], e1);
    }
  }
  ocls[p * 3 + 0] = a0; ocls[p * 3 + 1] = a1; ocls[p * 3 + 2] = a2;
  ooff[p * 3 + 0] = r0; ooff[p * 3 + 1] = r1; ooff[p * 3 + 2] = r2;
  oemb[p * 2 + 0] = e0; oemb[p * 2 + 1] = e1;
}

// ---------------- K6: exclusive scan over 2560 counts ----------------
__global__ void k_scan(const int* __restrict__ cnt, int* __restrict__ base) {
  __shared__ int csum[256];
  const int t = threadIdx.x;
  int loc[10]; int run = 0;
#pragma unroll
  for (int k = 0; k < 10; ++k) { loc[k] = cnt[t * 10 + k]; run += loc[k]; }
  csum[t] = run;
  __syncthreads();
  if (t == 0) {
    int acc = 0;
    for (int i = 0; i < 256; ++i) { int v = csum[i]; csum[i] = acc; acc += v; }
  }
  __syncthreads();
  int acc = csum[t];
#pragma unroll
  for (int k = 0; k < 10; ++k) {
    int idx = t * 10 + k;
    base[idx] = acc;
    acc += loc[k];
  }
}

// ---------------- K7: atomic-free scatter using precomputed ranks ----------------
__global__ void k_scatter(const int* __restrict__ seg, const int* __restrict__ rankp,
                          const int* __restrict__ base, int* __restrict__ order) {
  const int p = blockIdx.x * 256 + threadIdx.x;
  if (p < NPTS) order[base[seg[p]] + rankp[p]] = p;
}

// ---------------- K8: per-segment centroid + shape max + feat max (4 waves) ----------------
__global__ __launch_bounds__(256) void k_seg(const int* __restrict__ cnt, const int* __restrict__ base,
                      const int* __restrict__ order, const float* __restrict__ pts,
                      const unsigned short* __restrict__ pf,
                      const float* __restrict__ wsh, const float* __restrict__ bsh,
                      float* __restrict__ lf, float* __restrict__ centroid,
                      int* __restrict__ nonempty) {
  const int s = blockIdx.x;
  const int t = threadIdx.x, lane = t & 63, wv = t >> 6;
  const int n = cnt[s], bs = base[s];
  float sx = 0.f, sy = 0.f, sz = 0.f;
  for (int i = t; i < n; i += 256) {
    int p = order[bs + i];
    const float* pr = pts + (size_t)p * 9;
    sx += pr[1]; sy += pr[2]; sz += pr[3];
  }
#pragma unroll
  for (int m = 32; m > 0; m >>= 1) {
    sx += __shfl_xor(sx, m); sy += __shfl_xor(sy, m); sz += __shfl_xor(sz, m);
  }
  __shared__ float red[3][4];
  __shared__ float csh[3];
  if (lane == 0) { red[0][wv] = sx; red[1][wv] = sy; red[2][wv] = sz; }
  __syncthreads();
  if (t == 0) {
    float dn = (float)max(n, 1);
    csh[0] = (red[0][0] + red[0][1] + red[0][2] + red[0][3]) / dn;
    csh[1] = (red[1][0] + red[1][1] + red[1][2] + red[1][3]) / dn;
    csh[2] = (red[2][0] + red[2][1] + red[2][2] + red[2][3]) / dn;
  }
  __syncthreads();
  const float cx = csh[0], cy = csh[1], cz = csh[2];
  const float w0 = wsh[lane], w1 = wsh[64 + lane], w2 = wsh[128 + lane], bb = bsh[lane];
  float smax = -INFINITY, lmax = -INFINITY;
  for (int i = wv; i < n; i += 4) {
    int p = order[bs + i];
    const float* pr = pts + (size_t)p * 9;
    float sv = fmaf(pr[1] - cx, w0, fmaf(pr[2] - cy, w1, fmaf(pr[3] - cz, w2, bb)));
    smax = fmaxf(smax, sv);
    lmax = fmaxf(lmax, bf2f(pf[(size_t)p * 64 + lane]));
  }
  __shared__ float rs[4][64], rl[4][64];
  rs[wv][lane] = smax; rl[wv][lane] = lmax;
  __syncthreads();
  if (wv == 0) {
    smax = fmaxf(fmaxf(rs[0][lane], rs[1][lane]), fmaxf(rs[2][lane], rs[3][lane]));
    lmax = fmaxf(fmaxf(rl[0][lane], rl[1][lane]), fmaxf(rl[2][lane], rl[3][lane]));
    bool ne = n > 0;
    lf[s * 64 + lane] = (ne ? lmax : 0.f) + (ne ? smax : 0.f);
    if (lane == 0) {
      nonempty[s] = ne ? 1 : 0;
      centroid[s * 3 + 0] = cx; centroid[s * 3 + 1] = cy; centroid[s * 3 + 2] = cz;
    }
  }
}

// ---------------- K9: per-instance globals + sweep min/max + inst_mos ----------------
__global__ void k_glob(const float* __restrict__ lf, const int* __restrict__ ne,
                       const float* __restrict__ centroid,
                       const float* __restrict__ wmos, const float* __restrict__ bmos,
                       float* __restrict__ gf, float* __restrict__ tc, float* __restrict__ ic,
                       float* __restrict__ omos) {
  const int i = blockIdx.x;
  const int t = threadIdx.x; // 64 threads
  float g = -INFINITY;
  int maxsw = -1, minsw = 10;
  bool any = false;
#pragma unroll
  for (int s = 0; s < 10; ++s) {
    int idx = i * 10 + s;
    bool e = ne[idx] != 0;
    float v = lf[idx * 64 + t];
    g = fmaxf(g, e ? v : -INFINITY);
    if (e) { any = true; maxsw = s; minsw = min(minsw, s); }
  }
  float gv = any ? g : 0.f;
  gf[i * 64 + t] = gv;
  int idxmax = min(max(i * 10 + maxsw, 0), NSEG - 1);
  int idxmin = min(max(i * 10 + minsw, 0), NSEG - 1);
  float tcx = centroid[idxmax * 3 + 0], tcy = centroid[idxmax * 3 + 1], tcz = centroid[idxmax * 3 + 2];
  float icx = centroid[idxmin * 3 + 0], icy = centroid[idxmin * 3 + 1], icz = centroid[idxmin * 3 + 2];
  if (t == 0) {
    tc[i * 3 + 0] = tcx; tc[i * 3 + 1] = tcy; tc[i * 3 + 2] = tcz;
    ic[i * 3 + 0] = icx; ic[i * 3 + 1] = icy; ic[i * 3 + 2] = icz;
  }
  float r = gv * wmos[t];
#pragma unroll
  for (int m = 32; m > 0; m >>= 1) r += __shfl_xor(r, m);
  if (t == 0) {
    r += icx * wmos[64] + icy * wmos[65] + icz * wmos[66];
    r += tcx * wmos[67] + tcy * wmos[68] + tcz * wmos[69];
    omos[i] = r + bmos[0];
  }
}

// ---------------- K10: locals_tf = locals_cat(134) @ w_tf(134x7) ----------------
__global__ void k_tf(const float* __restrict__ lf, const float* __restrict__ gf,
                     const float* __restrict__ centroid, const float* __restrict__ tc,
                     const float* __restrict__ wtf, const float* __restrict__ btf,
                     float* __restrict__ otf) {
  const int r = blockIdx.x * 256 + threadIdx.x;
  if (r >= NSEG) return;
  const int i = r / 10;
  float acc[7];
#pragma unroll
  for (int j = 0; j < 7; ++j) acc[j] = btf[j];
  for (int k = 0; k < 64; ++k) {
    float v = lf[r * 64 + k];
#pragma unroll
    for (int j = 0; j < 7; ++j) acc[j] = fmaf(v, wtf[k * 7 + j], acc[j]);
  }
  for (int k = 0; k < 64; ++k) {
    float v = gf[i * 64 + k];
#pragma unroll
    for (int j = 0; j < 7; ++j) acc[j] = fmaf(v, wtf[(64 + k) * 7 + j], acc[j]);
  }
#pragma unroll
  for (int c = 0; c < 3; ++c) {
    float v = centroid[r * 3 + c];
#pragma unroll
    for (int j = 0; j < 7; ++j) acc[j] = fmaf(v, wtf[(128 + c) * 7 + j], acc[j]);
  }
#pragma unroll
  for (int c = 0; c < 3; ++c) {
    float v = tc[i * 3 + c];
#pragma unroll
    for (int j = 0; j < 7; ++j) acc[j] = fmaf(v, wtf[(131 + c) * 7 + j], acc[j]);
  }
#pragma unroll
  for (int j = 0; j < 7; ++j) otf[r * 7 + j] = acc[j];
}

extern "C" void kernel_launch(void* const* d_in, const int* in_sizes, int n_in,
                              void* d_out, int out_size, void* d_ws, size_t ws_size,
                              hipStream_t stream) {
  const float* pts   = (const float*)d_in[0];
  const float* x     = (const float*)d_in[1];
  const float* convw = (const float*)d_in[2];
  const float* gamma = (const float*)d_in[3];
  const float* beta  = (const float*)d_in[4];
  const float* wseg  = (const float*)d_in[5];
  const float* bseg  = (const float*)d_in[6];
  const float* wreg  = (const float*)d_in[7];
  const float* breg  = (const float*)d_in[8];
  const float* wemb  = (const float*)d_in[9];
  const float* bemb  = (const float*)d_in[10];
  const float* wsh   = (const float*)d_in[11];
  const float* bsh   = (const float*)d_in[12];
  const float* wtf   = (const float*)d_in[13];
  const float* btf   = (const float*)d_in[14];
  const float* wmos  = (const float*)d_in[15];
  const float* bmos  = (const float*)d_in[16];

  float* out = (float*)d_out;
  float* o_cls = out;                 // 400000 x 3
  float* o_off = out + 1200000;       // 400000 x 3
  float* o_emb = out + 2400000;       // 400000 x 2
  float* o_tf  = out + 3200000;       // 2560 x 7
  float* o_mos = out + 3217920;       // 256 x 1

  char* wsp = (char*)d_ws;
  size_t off = 0;
  auto alloc = [&](size_t bytes) -> void* {
    void* p = wsp + off;
    off = (off + bytes + 255) & ~(size_t)255;
    return p;
  };
  // xt dead after conv -> pf aliases it. y dead after bn2 -> rankp aliases it.
  unsigned short* xt   = (unsigned short*)alloc((size_t)4 * WID * WID * NCI * 2); // 66.4 MB
  unsigned short* pf   = xt;
  unsigned short* wbuf = (unsigned short*)alloc((size_t)9 * 64 * 256 * 2);
  unsigned short* y    = (unsigned short*)alloc((size_t)4 * HW * 64 * 2);         // 16.6 MB
  int*            rankp = (int*)y;
  unsigned short* bev  = (unsigned short*)alloc((size_t)4 * HW * 64 * 2);         // 16.6 MB
  int*   seg      = (int*)alloc((size_t)NPTS * 4);
  int*   order    = (int*)alloc((size_t)NPTS * 4);
  int*   cnt      = (int*)alloc(NSEG * 4);
  int*   base     = (int*)alloc(NSEG * 4);
  float* part     = (float*)alloc(256 * 64 * 2 * 4);
  float* ab       = (float*)alloc(64 * 2 * 4);
  float* centroid = (float*)alloc(NSEG * 3 * 4);
  float* lf       = (float*)alloc(NSEG * 64 * 4);
  int*   nonem    = (int*)alloc(NSEG * 4);
  float* gf       = (float*)alloc(NINST * 64 * 4);
  float* tc       = (float*)alloc(NINST * 3 * 4);
  float* ic       = (float*)alloc(NINST * 3 * 4);
  float* zbuf     = (float*)alloc(2048);
  (void)ws_size; (void)n_in; (void)in_sizes; (void)out_size;

  hipMemsetAsync(cnt, 0, NSEG * 4, stream);
  hipMemsetAsync(zbuf, 0, 2048, stream);

  k_transpose<<<dim3(12, WID, 4), 256, 0, stream>>>(x, xt);
  k_wreorg<<<576, 256, 0, stream>>>(convw, wbuf);
  k_conv_mfma<<<1440, 256, 0, stream>>>(xt, wbuf, zbuf, y);
  k_stats2<<<256, 256, 0, stream>>>(y, part);
  k_bnparams<<<1, 64, 0, stream>>>(part, gamma, beta, ab);
  k_bn2<<<(4 * HW * 8 + 255) / 256, 256, 0, stream>>>(y, ab, bev);
  k_points<<<25000, 256, 0, stream>>>(pts, bev, pf, seg, rankp, cnt);
  k_heads<<<(NPTS + 255) / 256, 256, 0, stream>>>(pf, wseg, bseg, wreg, breg, wemb, bemb,
                                                  o_cls, o_off, o_emb);
  k_scan<<<1, 256, 0, stream>>>(cnt, base);
  k_scatter<<<(NPTS + 255) / 256, 256, 0, stream>>>(seg, rankp, base, order);
  k_seg<<<NSEG, 256, 0, stream>>>(cnt, base, order, pts, pf, wsh, bsh, lf, centroid, nonem);
  k_glob<<<NINST, 64, 0, stream>>>(lf, nonem, centroid, wmos, bmos, gf, tc, ic, o_mos);
  k_tf<<<(NSEG + 255) / 256, 256, 0, stream>>>(lf, gf, centroid, tc, wtf, btf, o_tf);
}

// Round 5
// 382.960 us; speedup vs baseline: 5.0166x; 1.2654x over previous
//
#include <hip/hip_runtime.h>

typedef __attribute__((ext_vector_type(8))) unsigned short u16x8;
typedef __attribute__((ext_vector_type(8))) short s16x8;
typedef __attribute__((ext_vector_type(4))) float f32x4;

#define NPTS 400000
#define HW 32400
#define WID 180
#define NCI 256
#define NCO 64
#define NSEG 2560
#define NINST 256
#define NBLK 128
#define PPB 3125   // NBLK * PPB = 400000

__device__ __forceinline__ float bf2f(unsigned short u) {
  union { unsigned int i; float f; } v; v.i = ((unsigned int)u) << 16; return v.f;
}
__device__ __forceinline__ unsigned short f2bf(float f) {
  unsigned int u = __float_as_uint(f);
  return (unsigned short)((u + 0x7fffu + ((u >> 16) & 1u)) >> 16);
}

__device__ __forceinline__ void gld_lds16(const void* g, void* l) {
  __builtin_amdgcn_global_load_lds((const __attribute__((address_space(1))) void*)g,
                                   (__attribute__((address_space(3))) void*)l, 16, 0, 0);
}

// ---------------- K0: NCHW fp32 -> NHWC bf16 transpose ----------------
__global__ __launch_bounds__(256) void k_transpose(const float* __restrict__ x,
                                                   unsigned short* __restrict__ xt) {
  const int bw = blockIdx.x;            // 0..11: wtile = bw>>2, citile = bw&3
  const int h = blockIdx.y, b = blockIdx.z;
  const int w0 = (bw >> 2) * 64, ci0 = (bw & 3) * 64;
  __shared__ float tile[64][66];
  const int tid = threadIdx.x;
  const int tx = tid & 63, ty = tid >> 6;
  for (int cc = 0; cc < 16; ++cc) {
    int cl = cc * 4 + ty;
    float v = 0.f;
    int w = w0 + tx;
    if (w < WID) v = x[((size_t)(b * NCI + ci0 + cl) * WID + h) * WID + w];
    tile[tx][cl] = v;
  }
  __syncthreads();
  const int tx2 = tid & 31, ty2 = tid >> 5;
  for (int pp = 0; pp < 8; ++pp) {
    int wl = pp * 8 + ty2;
    int w = w0 + wl;
    if (w >= WID) continue;
    float f0 = tile[wl][2 * tx2], f1 = tile[wl][2 * tx2 + 1];
    unsigned int packed = (unsigned int)f2bf(f0) | ((unsigned int)f2bf(f1) << 16);
    *(unsigned int*)(xt + ((size_t)((b * WID + h) * WID + w)) * NCI + ci0 + 2 * tx2) = packed;
  }
}

// ---------------- K0b: conv_w [64][256][3][3] f32 -> wb[tap][co][ci] bf16 ----------------
__global__ void k_wreorg(const float* __restrict__ wt, unsigned short* __restrict__ wb) {
  int id = blockIdx.x * 256 + threadIdx.x;
  if (id >= 9 * 64 * 256) return;
  int ci = id & 255, co = (id >> 8) & 63, tap = id >> 14;
  wb[id] = f2bf(wt[((size_t)co * 256 + ci) * 9 + tap]);
}

// ---------------- K1: implicit-GEMM conv, double-buffered global_load_lds ----------------
#define RSTRIDE (104 * 128)
__global__ __launch_bounds__(256) void k_conv_mfma(const unsigned short* __restrict__ xt,
                                                   const unsigned short* __restrict__ wb,
                                                   const float* __restrict__ zbuf,
                                                   unsigned short* __restrict__ y) {
  const int wg = blockIdx.x;                    // 0..1439
  const int lin = (wg & 7) * 180 + (wg >> 3);   // bijective: 1440 = 8*180
  const int h = lin % 180;
  const int t2 = lin / 180;                     // b*2 + wth
  const int wth = t2 & 1, b = t2 >> 1;
  const int w0 = wth * 96;
  __shared__ unsigned char strip[2][3 * RSTRIDE];
  const int tid = threadIdx.x;
  const int lane = tid & 63, wv = tid >> 6;
  const int mh = wv >> 1, nh = wv & 1;
  const int l15 = lane & 15, lk = lane >> 4;
  const int l3 = lane >> 3, l7 = lane & 7;

  const char* srcs[10];
#pragma unroll
  for (int k = 0; k < 10; ++k) {
    int j = wv + k * 4;
    int row = j / 13, grp = j - row * 13;
    int hh = h + row - 1;
    int w_px = grp * 8 + l3;
    int worig = w0 + w_px - 1;
    bool valid = (j < 39) && (hh >= 0) && (hh < WID) && (worig >= 0) && (worig < WID);
    int sl = l7 ^ (w_px & 7);
    srcs[k] = valid
        ? (const char*)(xt + ((size_t)((b * WID + hh) * WID + worig)) * NCI + sl * 8)
        : (const char*)zbuf + lane * 16;
  }

  f32x4 acc[3][2];
#pragma unroll
  for (int i = 0; i < 3; ++i)
#pragma unroll
    for (int j = 0; j < 2; ++j) { acc[i][j][0] = 0.f; acc[i][j][1] = 0.f; acc[i][j][2] = 0.f; acc[i][j][3] = 0.f; }

  auto stage = [&](unsigned char* buf, int chunk) {
#pragma unroll
    for (int k = 0; k < 10; ++k) {
      int j = wv + k * 4;
      if (j >= 39) break;
      int row = j / 13, grp = j - row * 13;
      gld_lds16(srcs[k] + chunk * 128, buf + row * RSTRIDE + grp * 1024);
    }
  };

  stage(strip[0], 0);
  asm volatile("s_waitcnt vmcnt(0)" ::: "memory");
  __syncthreads();

  for (int chunk = 0; chunk < 4; ++chunk) {
    if (chunk < 3) stage(strip[(chunk + 1) & 1], chunk + 1);
    const unsigned char* buf = strip[chunk & 1];
    for (int tap = 0; tap < 9; ++tap) {
      const int dh = tap / 3, dw = tap % 3;
      const unsigned short* wbase = wb + (size_t)tap * (64 * 256) + chunk * 64;
#pragma unroll
      for (int kk = 0; kk < 2; ++kk) {
        s16x8 bfr[2];
#pragma unroll
        for (int nf = 0; nf < 2; ++nf) {
          int co = (nh * 2 + nf) * 16 + l15;
          bfr[nf] = *(const s16x8*)(wbase + (size_t)co * 256 + kk * 32 + lk * 8);
        }
        s16x8 afr[3];
#pragma unroll
        for (int i = 0; i < 3; ++i) {
          int wp = (mh * 3 + i) * 16 + l15 + dw;
          int byte = dh * RSTRIDE + wp * 128 + ((kk * 64 + lk * 16) ^ ((wp & 7) << 4));
          afr[i] = *(const s16x8*)(buf + byte);
        }
#pragma unroll
        for (int i = 0; i < 3; ++i)
#pragma unroll
          for (int nf = 0; nf < 2; ++nf)
            acc[i][nf] = __builtin_amdgcn_mfma_f32_16x16x32_bf16(afr[i], bfr[nf], acc[i][nf], 0, 0, 0);
      }
    }
    asm volatile("s_waitcnt vmcnt(0)" ::: "memory");
    __syncthreads();
  }

  const int r4 = lk * 4;
#pragma unroll
  for (int i = 0; i < 3; ++i) {
#pragma unroll
    for (int nf = 0; nf < 2; ++nf) {
      int co = (nh * 2 + nf) * 16 + l15;
#pragma unroll
      for (int j = 0; j < 4; ++j) {
        int w = w0 + (mh * 3 + i) * 16 + r4 + j;
        if (w < WID)
          y[((size_t)(b * HW) + h * WID + w) * 64 + co] = f2bf(acc[i][nf][j]);
      }
    }
  }
}

// ---------------- K2: BN partial stats over NHWC bf16 y ----------------
__global__ void k_stats2(const unsigned short* __restrict__ y, float* __restrict__ part) {
  const int t = threadIdx.x;
  const int c2 = (t & 31) * 2;
  const int g = t >> 5;
  float s0 = 0.f, s1 = 0.f, ss0 = 0.f, ss1 = 0.f;
  for (int r = blockIdx.x * 8 + g; r < 4 * HW; r += 256 * 8) {
    unsigned int v = *(const unsigned int*)(y + (size_t)r * 64 + c2);
    float f0 = bf2f((unsigned short)(v & 0xffffu));
    float f1 = bf2f((unsigned short)(v >> 16));
    s0 += f0; ss0 = fmaf(f0, f0, ss0);
    s1 += f1; ss1 = fmaf(f1, f1, ss1);
  }
  __shared__ float ls[8][64], lss[8][64];
  ls[g][c2] = s0; ls[g][c2 + 1] = s1;
  lss[g][c2] = ss0; lss[g][c2 + 1] = ss1;
  __syncthreads();
  if (t < 64) {
    float s = 0.f, ss = 0.f;
    for (int k = 0; k < 8; ++k) { s += ls[k][t]; ss += lss[k][t]; }
    part[(blockIdx.x * 64 + t) * 2] = s;
    part[(blockIdx.x * 64 + t) * 2 + 1] = ss;
  }
}

// ---------------- K2b: final BN scale/shift ----------------
__global__ void k_bnparams(const float* __restrict__ part, const float* __restrict__ gamma,
                           const float* __restrict__ beta, float* __restrict__ ab) {
  const int t = threadIdx.x; // 64
  float s = 0.f, ss = 0.f;
  for (int k = 0; k < 256; ++k) { s += part[(k * 64 + t) * 2]; ss += part[(k * 64 + t) * 2 + 1]; }
  float mu = s / 129600.f;
  float var = ss / 129600.f - mu * mu;
  float a = rsqrtf(var + 1e-5f) * gamma[t];
  ab[t * 2] = a; ab[t * 2 + 1] = beta[t] - mu * a;
}

// ---------------- K3: BN apply + ReLU (elementwise NHWC) ----------------
__global__ void k_bn2(const unsigned short* __restrict__ y, const float* __restrict__ ab,
                      unsigned short* __restrict__ bev) {
  __shared__ float sa[64], sb[64];
  const int t = threadIdx.x;
  if (t < 64) { sa[t] = ab[t * 2]; sb[t] = ab[t * 2 + 1]; }
  __syncthreads();
  size_t id = (size_t)blockIdx.x * 256 + t;
  if (id >= (size_t)4 * HW * 8) return;
  int c0 = (int)(id & 7) * 8;
  u16x8 v = *(const u16x8*)(y + id * 8);
  u16x8 o;
#pragma unroll
  for (int k = 0; k < 8; ++k) {
    float f = fmaf(bf2f(v[k]), sa[c0 + k], sb[c0 + k]);
    o[k] = f2bf(f > 0.f ? f : 0.f);
  }
  *(u16x8*)(bev + id * 8) = o;
}

// ---------------- K4: pure bilinear gather, 4 points/wave, no atomics ----------------
__global__ __launch_bounds__(256) void k_points(const float* __restrict__ pts,
                         const unsigned short* __restrict__ bev,
                         unsigned short* __restrict__ pf) {
  const int gid = blockIdx.x * 256 + threadIdx.x;
  const int lane = gid & 63;
  const int wid = gid >> 6;
#pragma unroll
  for (int it = 0; it < 4; ++it) {
    int p = wid * 4 + it;  // exactly covers 400000
    const float* pr = pts + (size_t)p * 9;
    float pbf = pr[0], xx = pr[1], yy = pr[2];
    int b = (int)pbf;
    float px = (xx - (-54.0f)) / 0.6f;
    float py = (yy - (-54.0f)) / 0.6f;
    int x0 = (int)floorf(px); x0 = min(max(x0, 0), WID - 1);
    int x1 = min(x0 + 1, WID - 1);
    int y0 = (int)floorf(py); y0 = min(max(y0, 0), WID - 1);
    int y1 = min(y0 + 1, WID - 1);
    float x0f = (float)x0, x1f = (float)x1, y0f = (float)y0, y1f = (float)y1;
    float wa = (x1f - px) * (y1f - py);
    float wb = (x1f - px) * (py - y0f);
    float wc = (px - x0f) * (y1f - py);
    float wd = (px - x0f) * (py - y0f);
    int i00 = y0 * WID + x0;
    int dx = x1 - x0;
    int dy = (y1 - y0) * WID;
    const unsigned short* bb = bev + ((size_t)b * HW) * 64 + lane;
    float Ia = bf2f(bb[(size_t)i00 * 64]);
    float Ic = bf2f(bb[(size_t)(i00 + dx) * 64]);
    float Ib = bf2f(bb[(size_t)(i00 + dy) * 64]);
    float Id = bf2f(bb[(size_t)(i00 + dy + dx) * 64]);
    float f = wa * Ia + wb * Ib + wc * Ic + wd * Id;
    pf[(size_t)p * 64 + lane] = f2bf(f);
  }
}

// ---------------- K4b: point heads (cls/offset/embedding) ----------------
__global__ void k_heads(const unsigned short* __restrict__ pf,
                        const float* __restrict__ wseg, const float* __restrict__ bseg,
                        const float* __restrict__ wreg, const float* __restrict__ breg,
                        const float* __restrict__ wemb, const float* __restrict__ bemb,
                        float* __restrict__ ocls, float* __restrict__ ooff, float* __restrict__ oemb) {
  const int p = blockIdx.x * 256 + threadIdx.x;
  if (p >= NPTS) return;
  float a0 = bseg[0], a1 = bseg[1], a2 = bseg[2];
  float r0 = breg[0], r1 = breg[1], r2 = breg[2];
  float e0 = bemb[0], e1 = bemb[1];
  const u16x8* q = (const u16x8*)(pf + (size_t)p * 64);
#pragma unroll
  for (int g = 0; g < 8; ++g) {
    u16x8 v8 = q[g];
#pragma unroll
    for (int k = 0; k < 8; ++k) {
      int kk = g * 8 + k;
      float v = bf2f(v8[k]);
      a0 = fmaf(v, wseg[kk * 3 + 0], a0);
      a1 = fmaf(v, wseg[kk * 3 + 1], a1);
      a2 = fmaf(v, wseg[kk * 3 + 2], a2);
      r0 = fmaf(v, wreg[kk * 3 + 0], r0);
      r1 = fmaf(v, wreg[kk * 3 + 1], r1);
      r2 = fmaf(v, wreg[kk * 3 + 2], r2);
      e0 = fmaf(v, wemb[kk * 2 + 0], e0);
      e1 = fmaf(v, wemb[kk * 2 + 1], e1);
    }
  }
  ocls[p * 3 + 0] = a0; ocls[p * 3 + 1] = a1; ocls[p * 3 + 2] = a2;
  ooff[p * 3 + 0] = r0; ooff[p * 3 + 1] = r1; ooff[p * 3 + 2] = r2;
  oemb[p * 2 + 0] = e0; oemb[p * 2 + 1] = e1;
}

// ---------------- K5: LDS-privatized histogram + local rank ----------------
__global__ __launch_bounds__(256) void k_hist2(const float* __restrict__ pts,
                                               int* __restrict__ seg, int* __restrict__ rankp,
                                               int* __restrict__ bh) {
  __shared__ int lc[NSEG];
  const int t = threadIdx.x, blk = blockIdx.x;
  for (int i = t; i < NSEG; i += 256) lc[i] = 0;
  __syncthreads();
  const int p0 = blk * PPB;
  for (int i = t; i < PPB; i += 256) {
    int p = p0 + i;
    const float* pr = pts + (size_t)p * 9;
    int b = (int)pr[0];
    int sw = (int)pr[6];
    int ins = (int)pr[7];
    int s = (b * 64 + ins) * 10 + sw;
    seg[p] = s;
    rankp[p] = atomicAdd(&lc[s], 1);
  }
  __syncthreads();
  for (int i = t; i < NSEG; i += 256) bh[i * NBLK + blk] = lc[i];
}

// ---------------- K6a: per-segment prefix across blocks ----------------
__global__ void k_scan2a(const int* __restrict__ bh, int* __restrict__ basebk,
                         int* __restrict__ tot) {
  const int s = blockIdx.x * 256 + threadIdx.x;  // 0..2559
  int acc = 0;
  for (int b = 0; b < NBLK; ++b) {
    int v = bh[s * NBLK + b];
    basebk[s * NBLK + b] = acc;
    acc += v;
  }
  tot[s] = acc;
}

// ---------------- K6b: exclusive scan of segment totals ----------------
__global__ void k_scan2b(const int* __restrict__ tot, int* __restrict__ base,
                         int* __restrict__ cnt) {
  __shared__ int csum[256];
  const int t = threadIdx.x;
  int loc[10]; int run = 0;
#pragma unroll
  for (int k = 0; k < 10; ++k) { loc[k] = tot[t * 10 + k]; run += loc[k]; }
  csum[t] = run;
  __syncthreads();
  if (t == 0) {
    int a = 0;
    for (int i = 0; i < 256; ++i) { int v = csum[i]; csum[i] = a; a += v; }
  }
  __syncthreads();
  int acc = csum[t];
#pragma unroll
  for (int k = 0; k < 10; ++k) {
    int s = t * 10 + k;
    base[s] = acc; cnt[s] = loc[k];
    acc += loc[k];
  }
}

// ---------------- K7: atomic-free scatter ----------------
__global__ void k_scatter2(const int* __restrict__ seg, const int* __restrict__ rankp,
                           const int* __restrict__ base, const int* __restrict__ basebk,
                           int* __restrict__ order) {
  const int p = blockIdx.x * 256 + threadIdx.x;
  if (p < NPTS) {
    int s = seg[p];
    int blk = p / PPB;
    order[base[s] + basebk[s * NBLK + blk] + rankp[p]] = p;
  }
}

// ---------------- K8: per-segment centroid + shape max + feat max (4 waves) ----------------
__global__ __launch_bounds__(256) void k_seg(const int* __restrict__ cnt, const int* __restrict__ base,
                      const int* __restrict__ order, const float* __restrict__ pts,
                      const unsigned short* __restrict__ pf,
                      const float* __restrict__ wsh, const float* __restrict__ bsh,
                      float* __restrict__ lf, float* __restrict__ centroid,
                      int* __restrict__ nonempty) {
  const int s = blockIdx.x;
  const int t = threadIdx.x, lane = t & 63, wv = t >> 6;
  const int n = cnt[s], bs = base[s];
  float sx = 0.f, sy = 0.f, sz = 0.f;
  for (int i = t; i < n; i += 256) {
    int p = order[bs + i];
    const float* pr = pts + (size_t)p * 9;
    sx += pr[1]; sy += pr[2]; sz += pr[3];
  }
#pragma unroll
  for (int m = 32; m > 0; m >>= 1) {
    sx += __shfl_xor(sx, m); sy += __shfl_xor(sy, m); sz += __shfl_xor(sz, m);
  }
  __shared__ float red[3][4];
  __shared__ float csh[3];
  if (lane == 0) { red[0][wv] = sx; red[1][wv] = sy; red[2][wv] = sz; }
  __syncthreads();
  if (t == 0) {
    float dn = (float)max(n, 1);
    csh[0] = (red[0][0] + red[0][1] + red[0][2] + red[0][3]) / dn;
    csh[1] = (red[1][0] + red[1][1] + red[1][2] + red[1][3]) / dn;
    csh[2] = (red[2][0] + red[2][1] + red[2][2] + red[2][3]) / dn;
  }
  __syncthreads();
  const float cx = csh[0], cy = csh[1], cz = csh[2];
  const float w0 = wsh[lane], w1 = wsh[64 + lane], w2 = wsh[128 + lane], bb = bsh[lane];
  float smax = -INFINITY, lmax = -INFINITY;
  for (int i = wv; i < n; i += 4) {
    int p = order[bs + i];
    const float* pr = pts + (size_t)p * 9;
    float sv = fmaf(pr[1] - cx, w0, fmaf(pr[2] - cy, w1, fmaf(pr[3] - cz, w2, bb)));
    smax = fmaxf(smax, sv);
    lmax = fmaxf(lmax, bf2f(pf[(size_t)p * 64 + lane]));
  }
  __shared__ float rs[4][64], rl[4][64];
  rs[wv][lane] = smax; rl[wv][lane] = lmax;
  __syncthreads();
  if (wv == 0) {
    smax = fmaxf(fmaxf(rs[0][lane], rs[1][lane]), fmaxf(rs[2][lane], rs[3][lane]));
    lmax = fmaxf(fmaxf(rl[0][lane], rl[1][lane]), fmaxf(rl[2][lane], rl[3][lane]));
    bool ne = n > 0;
    lf[s * 64 + lane] = (ne ? lmax : 0.f) + (ne ? smax : 0.f);
    if (lane == 0) {
      nonempty[s] = ne ? 1 : 0;
      centroid[s * 3 + 0] = cx; centroid[s * 3 + 1] = cy; centroid[s * 3 + 2] = cz;
    }
  }
}

// ---------------- K9: per-instance globals + sweep min/max + inst_mos ----------------
__global__ void k_glob(const float* __restrict__ lf, const int* __restrict__ ne,
                       const float* __restrict__ centroid,
                       const float* __restrict__ wmos, const float* __restrict__ bmos,
                       float* __restrict__ gf, float* __restrict__ tc, float* __restrict__ ic,
                       float* __restrict__ omos) {
  const int i = blockIdx.x;
  const int t = threadIdx.x; // 64 threads
  float g = -INFINITY;
  int maxsw = -1, minsw = 10;
  bool any = false;
#pragma unroll
  for (int s = 0; s < 10; ++s) {
    int idx = i * 10 + s;
    bool e = ne[idx] != 0;
    float v = lf[idx * 64 + t];
    g = fmaxf(g, e ? v : -INFINITY);
    if (e) { any = true; maxsw = s; minsw = min(minsw, s); }
  }
  float gv = any ? g : 0.f;
  gf[i * 64 + t] = gv;
  int idxmax = min(max(i * 10 + maxsw, 0), NSEG - 1);
  int idxmin = min(max(i * 10 + minsw, 0), NSEG - 1);
  float tcx = centroid[idxmax * 3 + 0], tcy = centroid[idxmax * 3 + 1], tcz = centroid[idxmax * 3 + 2];
  float icx = centroid[idxmin * 3 + 0], icy = centroid[idxmin * 3 + 1], icz = centroid[idxmin * 3 + 2];
  if (t == 0) {
    tc[i * 3 + 0] = tcx; tc[i * 3 + 1] = tcy; tc[i * 3 + 2] = tcz;
    ic[i * 3 + 0] = icx; ic[i * 3 + 1] = icy; ic[i * 3 + 2] = icz;
  }
  float r = gv * wmos[t];
#pragma unroll
  for (int m = 32; m > 0; m >>= 1) r += __shfl_xor(r, m);
  if (t == 0) {
    r += icx * wmos[64] + icy * wmos[65] + icz * wmos[66];
    r += tcx * wmos[67] + tcy * wmos[68] + tcz * wmos[69];
    omos[i] = r + bmos[0];
  }
}

// ---------------- K10: locals_tf = locals_cat(134) @ w_tf(134x7) ----------------
__global__ void k_tf(const float* __restrict__ lf, const float* __restrict__ gf,
                     const float* __restrict__ centroid, const float* __restrict__ tc,
                     const float* __restrict__ wtf, const float* __restrict__ btf,
                     float* __restrict__ otf) {
  const int r = blockIdx.x * 256 + threadIdx.x;
  if (r >= NSEG) return;
  const int i = r / 10;
  float acc[7];
#pragma unroll
  for (int j = 0; j < 7; ++j) acc[j] = btf[j];
  for (int k = 0; k < 64; ++k) {
    float v = lf[r * 64 + k];
#pragma unroll
    for (int j = 0; j < 7; ++j) acc[j] = fmaf(v, wtf[k * 7 + j], acc[j]);
  }
  for (int k = 0; k < 64; ++k) {
    float v = gf[i * 64 + k];
#pragma unroll
    for (int j = 0; j < 7; ++j) acc[j] = fmaf(v, wtf[(64 + k) * 7 + j], acc[j]);
  }
#pragma unroll
  for (int c = 0; c < 3; ++c) {
    float v = centroid[r * 3 + c];
#pragma unroll
    for (int j = 0; j < 7; ++j) acc[j] = fmaf(v, wtf[(128 + c) * 7 + j], acc[j]);
  }
#pragma unroll
  for (int c = 0; c < 3; ++c) {
    float v = tc[i * 3 + c];
#pragma unroll
    for (int j = 0; j < 7; ++j) acc[j] = fmaf(v, wtf[(131 + c) * 7 + j], acc[j]);
  }
#pragma unroll
  for (int j = 0; j < 7; ++j) otf[r * 7 + j] = acc[j];
}

extern "C" void kernel_launch(void* const* d_in, const int* in_sizes, int n_in,
                              void* d_out, int out_size, void* d_ws, size_t ws_size,
                              hipStream_t stream) {
  const float* pts   = (const float*)d_in[0];
  const float* x     = (const float*)d_in[1];
  const float* convw = (const float*)d_in[2];
  const float* gamma = (const float*)d_in[3];
  const float* beta  = (const float*)d_in[4];
  const float* wseg  = (const float*)d_in[5];
  const float* bseg  = (const float*)d_in[6];
  const float* wreg  = (const float*)d_in[7];
  const float* breg  = (const float*)d_in[8];
  const float* wemb  = (const float*)d_in[9];
  const float* bemb  = (const float*)d_in[10];
  const float* wsh   = (const float*)d_in[11];
  const float* bsh   = (const float*)d_in[12];
  const float* wtf   = (const float*)d_in[13];
  const float* btf   = (const float*)d_in[14];
  const float* wmos  = (const float*)d_in[15];
  const float* bmos  = (const float*)d_in[16];

  float* out = (float*)d_out;
  float* o_cls = out;                 // 400000 x 3
  float* o_off = out + 1200000;       // 400000 x 3
  float* o_emb = out + 2400000;       // 400000 x 2
  float* o_tf  = out + 3200000;       // 2560 x 7
  float* o_mos = out + 3217920;       // 256 x 1

  char* wsp = (char*)d_ws;
  size_t off = 0;
  auto alloc = [&](size_t bytes) -> void* {
    void* p = wsp + off;
    off = (off + bytes + 255) & ~(size_t)255;
    return p;
  };
  // xt dead after conv -> pf aliases it.
  unsigned short* xt   = (unsigned short*)alloc((size_t)4 * WID * WID * NCI * 2); // 66.4 MB
  unsigned short* pf   = xt;
  unsigned short* wbuf = (unsigned short*)alloc((size_t)9 * 64 * 256 * 2);
  unsigned short* y    = (unsigned short*)alloc((size_t)4 * HW * 64 * 2);         // 16.6 MB
  unsigned short* bev  = (unsigned short*)alloc((size_t)4 * HW * 64 * 2);         // 16.6 MB
  int*   seg      = (int*)alloc((size_t)NPTS * 4);
  int*   rankp    = (int*)alloc((size_t)NPTS * 4);
  int*   order    = (int*)alloc((size_t)NPTS * 4);
  int*   bh       = (int*)alloc((size_t)NSEG * NBLK * 4);   // 1.31 MB
  int*   basebk   = (int*)alloc((size_t)NSEG * NBLK * 4);   // 1.31 MB
  int*   tot      = (int*)alloc(NSEG * 4);
  int*   cnt      = (int*)alloc(NSEG * 4);
  int*   base     = (int*)alloc(NSEG * 4);
  float* part     = (float*)alloc(256 * 64 * 2 * 4);
  float* ab       = (float*)alloc(64 * 2 * 4);
  float* centroid = (float*)alloc(NSEG * 3 * 4);
  float* lf       = (float*)alloc(NSEG * 64 * 4);
  int*   nonem    = (int*)alloc(NSEG * 4);
  float* gf       = (float*)alloc(NINST * 64 * 4);
  float* tc       = (float*)alloc(NINST * 3 * 4);
  float* ic       = (float*)alloc(NINST * 3 * 4);
  float* zbuf     = (float*)alloc(2048);
  (void)ws_size; (void)n_in; (void)in_sizes; (void)out_size;

  hipMemsetAsync(zbuf, 0, 2048, stream);

  k_hist2<<<NBLK, 256, 0, stream>>>(pts, seg, rankp, bh);
  k_scan2a<<<10, 256, 0, stream>>>(bh, basebk, tot);
  k_scan2b<<<1, 256, 0, stream>>>(tot, base, cnt);
  k_scatter2<<<(NPTS + 255) / 256, 256, 0, stream>>>(seg, rankp, base, basebk, order);
  k_transpose<<<dim3(12, WID, 4), 256, 0, stream>>>(x, xt);
  k_wreorg<<<576, 256, 0, stream>>>(convw, wbuf);
  k_conv_mfma<<<1440, 256, 0, stream>>>(xt, wbuf, zbuf, y);
  k_stats2<<<256, 256, 0, stream>>>(y, part);
  k_bnparams<<<1, 64, 0, stream>>>(part, gamma, beta, ab);
  k_bn2<<<(4 * HW * 8 + 255) / 256, 256, 0, stream>>>(y, ab, bev);
  k_points<<<25000, 256, 0, stream>>>(pts, bev, pf);
  k_heads<<<(NPTS + 255) / 256, 256, 0, stream>>>(pf, wseg, bseg, wreg, breg, wemb, bemb,
                                                  o_cls, o_off, o_emb);
  k_seg<<<NSEG, 256, 0, stream>>>(cnt, base, order, pts, pf, wsh, bsh, lf, centroid, nonem);
  k_glob<<<NINST, 64, 0, stream>>>(lf, nonem, centroid, wmos, bmos, gf, tc, ic, o_mos);
  k_tf<<<(NSEG + 255) / 256, 256, 0, stream>>>(lf, gf, centroid, tc, wtf, btf, o_tf);
}

// Round 6
// 380.600 us; speedup vs baseline: 5.0477x; 1.0062x over previous
//
#include <hip/hip_runtime.h>

typedef __attribute__((ext_vector_type(8))) unsigned short u16x8;
typedef __attribute__((ext_vector_type(8))) short s16x8;
typedef __attribute__((ext_vector_type(4))) float f32x4;

#define NPTS 400000
#define HW 32400
#define WID 180
#define NCI 256
#define NCO 64
#define NSEG 2560
#define NINST 256
#define NBLK 128
#define PPB 3125   // NBLK * PPB = 400000

__device__ __forceinline__ float bf2f(unsigned short u) {
  union { unsigned int i; float f; } v; v.i = ((unsigned int)u) << 16; return v.f;
}
__device__ __forceinline__ unsigned short f2bf(float f) {
  unsigned int u = __float_as_uint(f);
  return (unsigned short)((u + 0x7fffu + ((u >> 16) & 1u)) >> 16);
}

__device__ __forceinline__ void gld_lds16(const void* g, void* l) {
  __builtin_amdgcn_global_load_lds((const __attribute__((address_space(1))) void*)g,
                                   (__attribute__((address_space(3))) void*)l, 16, 0, 0);
}

// ---------------- K0: NCHW fp32 -> NHWC bf16 transpose ----------------
__global__ __launch_bounds__(256) void k_transpose(const float* __restrict__ x,
                                                   unsigned short* __restrict__ xt) {
  const int bw = blockIdx.x;            // 0..11: wtile = bw>>2, citile = bw&3
  const int h = blockIdx.y, b = blockIdx.z;
  const int w0 = (bw >> 2) * 64, ci0 = (bw & 3) * 64;
  __shared__ float tile[64][66];
  const int tid = threadIdx.x;
  const int tx = tid & 63, ty = tid >> 6;
  for (int cc = 0; cc < 16; ++cc) {
    int cl = cc * 4 + ty;
    float v = 0.f;
    int w = w0 + tx;
    if (w < WID) v = x[((size_t)(b * NCI + ci0 + cl) * WID + h) * WID + w];
    tile[tx][cl] = v;
  }
  __syncthreads();
  const int tx2 = tid & 31, ty2 = tid >> 5;
  for (int pp = 0; pp < 8; ++pp) {
    int wl = pp * 8 + ty2;
    int w = w0 + wl;
    if (w >= WID) continue;
    float f0 = tile[wl][2 * tx2], f1 = tile[wl][2 * tx2 + 1];
    unsigned int packed = (unsigned int)f2bf(f0) | ((unsigned int)f2bf(f1) << 16);
    *(unsigned int*)(xt + ((size_t)((b * WID + h) * WID + w)) * NCI + ci0 + 2 * tx2) = packed;
  }
}

// ---------------- K0b: conv_w [64][256][3][3] f32 -> wb[tap][co][ci] bf16 ----------------
__global__ void k_wreorg(const float* __restrict__ wt, unsigned short* __restrict__ wb) {
  int id = blockIdx.x * 256 + threadIdx.x;
  if (id >= 9 * 64 * 256) return;
  int ci = id & 255, co = (id >> 8) & 63, tap = id >> 14;
  wb[id] = f2bf(wt[((size_t)co * 256 + ci) * 9 + tap]);
}

// ---------------- K1: implicit-GEMM conv, dbuf gld_lds + hoisted B-frags ----------------
#define RSTRIDE (104 * 128)
__global__ __launch_bounds__(256) void k_conv_mfma(const unsigned short* __restrict__ xt,
                                                   const unsigned short* __restrict__ wb,
                                                   const float* __restrict__ zbuf,
                                                   unsigned short* __restrict__ y) {
  const int wg = blockIdx.x;                    // 0..1439
  const int lin = (wg & 7) * 180 + (wg >> 3);   // bijective: 1440 = 8*180
  const int h = lin % 180;
  const int t2 = lin / 180;                     // b*2 + wth
  const int wth = t2 & 1, b = t2 >> 1;
  const int w0 = wth * 96;
  __shared__ unsigned char strip[2][3 * RSTRIDE];
  const int tid = threadIdx.x;
  const int lane = tid & 63, wv = tid >> 6;
  const int mh = wv >> 1, nh = wv & 1;
  const int l15 = lane & 15, lk = lane >> 4;
  const int l3 = lane >> 3, l7 = lane & 7;

  const char* srcs[10];
#pragma unroll
  for (int k = 0; k < 10; ++k) {
    int j = wv + k * 4;
    int row = j / 13, grp = j - row * 13;
    int hh = h + row - 1;
    int w_px = grp * 8 + l3;
    int worig = w0 + w_px - 1;
    bool valid = (j < 39) && (hh >= 0) && (hh < WID) && (worig >= 0) && (worig < WID);
    int sl = l7 ^ (w_px & 7);
    srcs[k] = valid
        ? (const char*)(xt + ((size_t)((b * WID + hh) * WID + worig)) * NCI + sl * 8)
        : (const char*)zbuf + lane * 16;
  }

  f32x4 acc[3][2];
#pragma unroll
  for (int i = 0; i < 3; ++i)
#pragma unroll
    for (int j = 0; j < 2; ++j) { acc[i][j][0] = 0.f; acc[i][j][1] = 0.f; acc[i][j][2] = 0.f; acc[i][j][3] = 0.f; }

  auto stage = [&](unsigned char* buf, int chunk) {
#pragma unroll
    for (int k = 0; k < 10; ++k) {
      int j = wv + k * 4;
      if (j >= 39) break;
      int row = j / 13, grp = j - row * 13;
      gld_lds16(srcs[k] + chunk * 128, buf + row * RSTRIDE + grp * 1024);
    }
  };

  stage(strip[0], 0);
  asm volatile("s_waitcnt vmcnt(0)" ::: "memory");
  __syncthreads();

  // per-wave weight base: co = (nh*2+nf)*16 + l15, element offset co*256 + lk*8
  const unsigned short* wco[2];
#pragma unroll
  for (int nf = 0; nf < 2; ++nf)
    wco[nf] = wb + (size_t)((nh * 2 + nf) * 16 + l15) * 256 + lk * 8;

  for (int chunk = 0; chunk < 4; ++chunk) {
    if (chunk < 3) stage(strip[(chunk + 1) & 1], chunk + 1);
    const unsigned char* buf = strip[chunk & 1];
#pragma unroll
    for (int kk = 0; kk < 2; ++kk) {
      // hoist ALL 18 B-frags for this kk: one pipelined global burst
      s16x8 bfr[9][2];
#pragma unroll
      for (int tap = 0; tap < 9; ++tap)
#pragma unroll
        for (int nf = 0; nf < 2; ++nf)
          bfr[tap][nf] = *(const s16x8*)(wco[nf] + (size_t)tap * (64 * 256) + chunk * 64 + kk * 32);
#pragma unroll
      for (int tap = 0; tap < 9; ++tap) {
        const int dh = tap / 3, dw = tap % 3;
        s16x8 afr[3];
#pragma unroll
        for (int i = 0; i < 3; ++i) {
          int wp = (mh * 3 + i) * 16 + l15 + dw;
          int byte = dh * RSTRIDE + wp * 128 + ((kk * 64 + lk * 16) ^ ((wp & 7) << 4));
          afr[i] = *(const s16x8*)(buf + byte);
        }
#pragma unroll
        for (int i = 0; i < 3; ++i)
#pragma unroll
          for (int nf = 0; nf < 2; ++nf)
            acc[i][nf] = __builtin_amdgcn_mfma_f32_16x16x32_bf16(afr[i], bfr[tap][nf], acc[i][nf], 0, 0, 0);
      }
    }
    asm volatile("s_waitcnt vmcnt(0)" ::: "memory");
    __syncthreads();
  }

  const int r4 = lk * 4;
#pragma unroll
  for (int i = 0; i < 3; ++i) {
#pragma unroll
    for (int nf = 0; nf < 2; ++nf) {
      int co = (nh * 2 + nf) * 16 + l15;
#pragma unroll
      for (int j = 0; j < 4; ++j) {
        int w = w0 + (mh * 3 + i) * 16 + r4 + j;
        if (w < WID)
          y[((size_t)(b * HW) + h * WID + w) * 64 + co] = f2bf(acc[i][nf][j]);
      }
    }
  }
}

// ---------------- K2: BN partial stats over NHWC bf16 y ----------------
__global__ void k_stats2(const unsigned short* __restrict__ y, float* __restrict__ part) {
  const int t = threadIdx.x;
  const int c2 = (t & 31) * 2;
  const int g = t >> 5;
  float s0 = 0.f, s1 = 0.f, ss0 = 0.f, ss1 = 0.f;
  for (int r = blockIdx.x * 8 + g; r < 4 * HW; r += 256 * 8) {
    unsigned int v = *(const unsigned int*)(y + (size_t)r * 64 + c2);
    float f0 = bf2f((unsigned short)(v & 0xffffu));
    float f1 = bf2f((unsigned short)(v >> 16));
    s0 += f0; ss0 = fmaf(f0, f0, ss0);
    s1 += f1; ss1 = fmaf(f1, f1, ss1);
  }
  __shared__ float ls[8][64], lss[8][64];
  ls[g][c2] = s0; ls[g][c2 + 1] = s1;
  lss[g][c2] = ss0; lss[g][c2 + 1] = ss1;
  __syncthreads();
  if (t < 64) {
    float s = 0.f, ss = 0.f;
    for (int k = 0; k < 8; ++k) { s += ls[k][t]; ss += lss[k][t]; }
    part[(blockIdx.x * 64 + t) * 2] = s;
    part[(blockIdx.x * 64 + t) * 2 + 1] = ss;
  }
}

// ---------------- K2b: final BN scale/shift ----------------
__global__ void k_bnparams(const float* __restrict__ part, const float* __restrict__ gamma,
                           const float* __restrict__ beta, float* __restrict__ ab) {
  const int t = threadIdx.x; // 64
  float s = 0.f, ss = 0.f;
  for (int k = 0; k < 256; ++k) { s += part[(k * 64 + t) * 2]; ss += part[(k * 64 + t) * 2 + 1]; }
  float mu = s / 129600.f;
  float var = ss / 129600.f - mu * mu;
  float a = rsqrtf(var + 1e-5f) * gamma[t];
  ab[t * 2] = a; ab[t * 2 + 1] = beta[t] - mu * a;
}

// ---------------- K3: BN apply + ReLU (elementwise NHWC) ----------------
__global__ void k_bn2(const unsigned short* __restrict__ y, const float* __restrict__ ab,
                      unsigned short* __restrict__ bev) {
  __shared__ float sa[64], sb[64];
  const int t = threadIdx.x;
  if (t < 64) { sa[t] = ab[t * 2]; sb[t] = ab[t * 2 + 1]; }
  __syncthreads();
  size_t id = (size_t)blockIdx.x * 256 + t;
  if (id >= (size_t)4 * HW * 8) return;
  int c0 = (int)(id & 7) * 8;
  u16x8 v = *(const u16x8*)(y + id * 8);
  u16x8 o;
#pragma unroll
  for (int k = 0; k < 8; ++k) {
    float f = fmaf(bf2f(v[k]), sa[c0 + k], sb[c0 + k]);
    o[k] = f2bf(f > 0.f ? f : 0.f);
  }
  *(u16x8*)(bev + id * 8) = o;
}

// ---------------- K4: pure bilinear gather, 4 points/wave, no atomics ----------------
__global__ __launch_bounds__(256) void k_points(const float* __restrict__ pts,
                         const unsigned short* __restrict__ bev,
                         unsigned short* __restrict__ pf) {
  const int gid = blockIdx.x * 256 + threadIdx.x;
  const int lane = gid & 63;
  const int wid = gid >> 6;
#pragma unroll
  for (int it = 0; it < 4; ++it) {
    int p = wid * 4 + it;  // exactly covers 400000
    const float* pr = pts + (size_t)p * 9;
    float pbf = pr[0], xx = pr[1], yy = pr[2];
    int b = (int)pbf;
    float px = (xx - (-54.0f)) / 0.6f;
    float py = (yy - (-54.0f)) / 0.6f;
    int x0 = (int)floorf(px); x0 = min(max(x0, 0), WID - 1);
    int x1 = min(x0 + 1, WID - 1);
    int y0 = (int)floorf(py); y0 = min(max(y0, 0), WID - 1);
    int y1 = min(y0 + 1, WID - 1);
    float x0f = (float)x0, x1f = (float)x1, y0f = (float)y0, y1f = (float)y1;
    float wa = (x1f - px) * (y1f - py);
    float wb = (x1f - px) * (py - y0f);
    float wc = (px - x0f) * (y1f - py);
    float wd = (px - x0f) * (py - y0f);
    int i00 = y0 * WID + x0;
    int dx = x1 - x0;
    int dy = (y1 - y0) * WID;
    const unsigned short* bb = bev + ((size_t)b * HW) * 64 + lane;
    float Ia = bf2f(bb[(size_t)i00 * 64]);
    float Ic = bf2f(bb[(size_t)(i00 + dx) * 64]);
    float Ib = bf2f(bb[(size_t)(i00 + dy) * 64]);
    float Id = bf2f(bb[(size_t)(i00 + dy + dx) * 64]);
    float f = wa * Ia + wb * Ib + wc * Ic + wd * Id;
    pf[(size_t)p * 64 + lane] = f2bf(f);
  }
}

// ---------------- K4b: point heads (cls/offset/embedding) ----------------
__global__ void k_heads(const unsigned short* __restrict__ pf,
                        const float* __restrict__ wseg, const float* __restrict__ bseg,
                        const float* __restrict__ wreg, const float* __restrict__ breg,
                        const float* __restrict__ wemb, const float* __restrict__ bemb,
                        float* __restrict__ ocls, float* __restrict__ ooff, float* __restrict__ oemb) {
  const int p = blockIdx.x * 256 + threadIdx.x;
  if (p >= NPTS) return;
  float a0 = bseg[0], a1 = bseg[1], a2 = bseg[2];
  float r0 = breg[0], r1 = breg[1], r2 = breg[2];
  float e0 = bemb[0], e1 = bemb[1];
  const u16x8* q = (const u16x8*)(pf + (size_t)p * 64);
#pragma unroll
  for (int g = 0; g < 8; ++g) {
    u16x8 v8 = q[g];
#pragma unroll
    for (int k = 0; k < 8; ++k) {
      int kk = g * 8 + k;
      float v = bf2f(v8[k]);
      a0 = fmaf(v, wseg[kk * 3 + 0], a0);
      a1 = fmaf(v, wseg[kk * 3 + 1], a1);
      a2 = fmaf(v, wseg[kk * 3 + 2], a2);
      r0 = fmaf(v, wreg[kk * 3 + 0], r0);
      r1 = fmaf(v, wreg[kk * 3 + 1], r1);
      r2 = fmaf(v, wreg[kk * 3 + 2], r2);
      e0 = fmaf(v, wemb[kk * 2 + 0], e0);
      e1 = fmaf(v, wemb[kk * 2 + 1], e1);
    }
  }
  ocls[p * 3 + 0] = a0; ocls[p * 3 + 1] = a1; ocls[p * 3 + 2] = a2;
  ooff[p * 3 + 0] = r0; ooff[p * 3 + 1] = r1; ooff[p * 3 + 2] = r2;
  oemb[p * 2 + 0] = e0; oemb[p * 2 + 1] = e1;
}

// ---------------- K5: LDS-privatized histogram + local rank ----------------
__global__ __launch_bounds__(256) void k_hist2(const float* __restrict__ pts,
                                               int* __restrict__ seg, int* __restrict__ rankp,
                                               int* __restrict__ bh) {
  __shared__ int lc[NSEG];
  const int t = threadIdx.x, blk = blockIdx.x;
  for (int i = t; i < NSEG; i += 256) lc[i] = 0;
  __syncthreads();
  const int p0 = blk * PPB;
  for (int i = t; i < PPB; i += 256) {
    int p = p0 + i;
    const float* pr = pts + (size_t)p * 9;
    int b = (int)pr[0];
    int sw = (int)pr[6];
    int ins = (int)pr[7];
    int s = (b * 64 + ins) * 10 + sw;
    seg[p] = s;
    rankp[p] = atomicAdd(&lc[s], 1);
  }
  __syncthreads();
  for (int i = t; i < NSEG; i += 256) bh[i * NBLK + blk] = lc[i];
}

// ---------------- K6a: per-segment prefix across blocks ----------------
__global__ void k_scan2a(const int* __restrict__ bh, int* __restrict__ basebk,
                         int* __restrict__ tot) {
  const int s = blockIdx.x * 256 + threadIdx.x;  // 0..2559
  int acc = 0;
  for (int b = 0; b < NBLK; ++b) {
    int v = bh[s * NBLK + b];
    basebk[s * NBLK + b] = acc;
    acc += v;
  }
  tot[s] = acc;
}

// ---------------- K6b: exclusive scan of segment totals ----------------
__global__ void k_scan2b(const int* __restrict__ tot, int* __restrict__ base,
                         int* __restrict__ cnt) {
  __shared__ int csum[256];
  const int t = threadIdx.x;
  int loc[10]; int run = 0;
#pragma unroll
  for (int k = 0; k < 10; ++k) { loc[k] = tot[t * 10 + k]; run += loc[k]; }
  csum[t] = run;
  __syncthreads();
  if (t == 0) {
    int a = 0;
    for (int i = 0; i < 256; ++i) { int v = csum[i]; csum[i] = a; a += v; }
  }
  __syncthreads();
  int acc = csum[t];
#pragma unroll
  for (int k = 0; k < 10; ++k) {
    int s = t * 10 + k;
    base[s] = acc; cnt[s] = loc[k];
    acc += loc[k];
  }
}

// ---------------- K7: atomic-free scatter ----------------
__global__ void k_scatter2(const int* __restrict__ seg, const int* __restrict__ rankp,
                           const int* __restrict__ base, const int* __restrict__ basebk,
                           int* __restrict__ order) {
  const int p = blockIdx.x * 256 + threadIdx.x;
  if (p < NPTS) {
    int s = seg[p];
    int blk = p / PPB;
    order[base[s] + basebk[s * NBLK + blk] + rankp[p]] = p;
  }
}

// ---------------- K8: per-segment centroid + shape max + feat max (4 waves) ----------------
__global__ __launch_bounds__(256) void k_seg(const int* __restrict__ cnt, const int* __restrict__ base,
                      const int* __restrict__ order, const float* __restrict__ pts,
                      const unsigned short* __restrict__ pf,
                      const float* __restrict__ wsh, const float* __restrict__ bsh,
                      float* __restrict__ lf, float* __restrict__ centroid,
                      int* __restrict__ nonempty) {
  const int s = blockIdx.x;
  const int t = threadIdx.x, lane = t & 63, wv = t >> 6;
  const int n = cnt[s], bs = base[s];
  float sx = 0.f, sy = 0.f, sz = 0.f;
  for (int i = t; i < n; i += 256) {
    int p = order[bs + i];
    const float* pr = pts + (size_t)p * 9;
    sx += pr[1]; sy += pr[2]; sz += pr[3];
  }
#pragma unroll
  for (int m = 32; m > 0; m >>= 1) {
    sx += __shfl_xor(sx, m); sy += __shfl_xor(sy, m); sz += __shfl_xor(sz, m);
  }
  __shared__ float red[3][4];
  __shared__ float csh[3];
  if (lane == 0) { red[0][wv] = sx; red[1][wv] = sy; red[2][wv] = sz; }
  __syncthreads();
  if (t == 0) {
    float dn = (float)max(n, 1);
    csh[0] = (red[0][0] + red[0][1] + red[0][2] + red[0][3]) / dn;
    csh[1] = (red[1][0] + red[1][1] + red[1][2] + red[1][3]) / dn;
    csh[2] = (red[2][0] + red[2][1] + red[2][2] + red[2][3]) / dn;
  }
  __syncthreads();
  const float cx = csh[0], cy = csh[1], cz = csh[2];
  const float w0 = wsh[lane], w1 = wsh[64 + lane], w2 = wsh[128 + lane], bb = bsh[lane];
  float smax = -INFINITY, lmax = -INFINITY;
  for (int i = wv; i < n; i += 4) {
    int p = order[bs + i];
    const float* pr = pts + (size_t)p * 9;
    float sv = fmaf(pr[1] - cx, w0, fmaf(pr[2] - cy, w1, fmaf(pr[3] - cz, w2, bb)));
    smax = fmaxf(smax, sv);
    lmax = fmaxf(lmax, bf2f(pf[(size_t)p * 64 + lane]));
  }
  __shared__ float rs[4][64], rl[4][64];
  rs[wv][lane] = smax; rl[wv][lane] = lmax;
  __syncthreads();
  if (wv == 0) {
    smax = fmaxf(fmaxf(rs[0][lane], rs[1][lane]), fmaxf(rs[2][lane], rs[3][lane]));
    lmax = fmaxf(fmaxf(rl[0][lane], rl[1][lane]), fmaxf(rl[2][lane], rl[3][lane]));
    bool ne = n > 0;
    lf[s * 64 + lane] = (ne ? lmax : 0.f) + (ne ? smax : 0.f);
    if (lane == 0) {
      nonempty[s] = ne ? 1 : 0;
      centroid[s * 3 + 0] = cx; centroid[s * 3 + 1] = cy; centroid[s * 3 + 2] = cz;
    }
  }
}

// ---------------- K9: per-instance globals + sweep min/max + inst_mos ----------------
__global__ void k_glob(const float* __restrict__ lf, const int* __restrict__ ne,
                       const float* __restrict__ centroid,
                       const float* __restrict__ wmos, const float* __restrict__ bmos,
                       float* __restrict__ gf, float* __restrict__ tc, float* __restrict__ ic,
                       float* __restrict__ omos) {
  const int i = blockIdx.x;
  const int t = threadIdx.x; // 64 threads
  float g = -INFINITY;
  int maxsw = -1, minsw = 10;
  bool any = false;
#pragma unroll
  for (int s = 0; s < 10; ++s) {
    int idx = i * 10 + s;
    bool e = ne[idx] != 0;
    float v = lf[idx * 64 + t];
    g = fmaxf(g, e ? v : -INFINITY);
    if (e) { any = true; maxsw = s; minsw = min(minsw, s); }
  }
  float gv = any ? g : 0.f;
  gf[i * 64 + t] = gv;
  int idxmax = min(max(i * 10 + maxsw, 0), NSEG - 1);
  int idxmin = min(max(i * 10 + minsw, 0), NSEG - 1);
  float tcx = centroid[idxmax * 3 + 0], tcy = centroid[idxmax * 3 + 1], tcz = centroid[idxmax * 3 + 2];
  float icx = centroid[idxmin * 3 + 0], icy = centroid[idxmin * 3 + 1], icz = centroid[idxmin * 3 + 2];
  if (t == 0) {
    tc[i * 3 + 0] = tcx; tc[i * 3 + 1] = tcy; tc[i * 3 + 2] = tcz;
    ic[i * 3 + 0] = icx; ic[i * 3 + 1] = icy; ic[i * 3 + 2] = icz;
  }
  float r = gv * wmos[t];
#pragma unroll
  for (int m = 32; m > 0; m >>= 1) r += __shfl_xor(r, m);
  if (t == 0) {
    r += icx * wmos[64] + icy * wmos[65] + icz * wmos[66];
    r += tcx * wmos[67] + tcy * wmos[68] + tcz * wmos[69];
    omos[i] = r + bmos[0];
  }
}

// ---------------- K10: locals_tf = locals_cat(134) @ w_tf(134x7) ----------------
__global__ void k_tf(const float* __restrict__ lf, const float* __restrict__ gf,
                     const float* __restrict__ centroid, const float* __restrict__ tc,
                     const float* __restrict__ wtf, const float* __restrict__ btf,
                     float* __restrict__ otf) {
  const int r = blockIdx.x * 256 + threadIdx.x;
  if (r >= NSEG) return;
  const int i = r / 10;
  float acc[7];
#pragma unroll
  for (int j = 0; j < 7; ++j) acc[j] = btf[j];
  for (int k = 0; k < 64; ++k) {
    float v = lf[r * 64 + k];
#pragma unroll
    for (int j = 0; j < 7; ++j) acc[j] = fmaf(v, wtf[k * 7 + j], acc[j]);
  }
  for (int k = 0; k < 64; ++k) {
    float v = gf[i * 64 + k];
#pragma unroll
    for (int j = 0; j < 7; ++j) acc[j] = fmaf(v, wtf[(64 + k) * 7 + j], acc[j]);
  }
#pragma unroll
  for (int c = 0; c < 3; ++c) {
    float v = centroid[r * 3 + c];
#pragma unroll
    for (int j = 0; j < 7; ++j) acc[j] = fmaf(v, wtf[(128 + c) * 7 + j], acc[j]);
  }
#pragma unroll
  for (int c = 0; c < 3; ++c) {
    float v = tc[i * 3 + c];
#pragma unroll
    for (int j = 0; j < 7; ++j) acc[j] = fmaf(v, wtf[(131 + c) * 7 + j], acc[j]);
  }
#pragma unroll
  for (int j = 0; j < 7; ++j) otf[r * 7 + j] = acc[j];
}

extern "C" void kernel_launch(void* const* d_in, const int* in_sizes, int n_in,
                              void* d_out, int out_size, void* d_ws, size_t ws_size,
                              hipStream_t stream) {
  const float* pts   = (const float*)d_in[0];
  const float* x     = (const float*)d_in[1];
  const float* convw = (const float*)d_in[2];
  const float* gamma = (const float*)d_in[3];
  const float* beta  = (const float*)d_in[4];
  const float* wseg  = (const float*)d_in[5];
  const float* bseg  = (const float*)d_in[6];
  const float* wreg  = (const float*)d_in[7];
  const float* breg  = (const float*)d_in[8];
  const float* wemb  = (const float*)d_in[9];
  const float* bemb  = (const float*)d_in[10];
  const float* wsh   = (const float*)d_in[11];
  const float* bsh   = (const float*)d_in[12];
  const float* wtf   = (const float*)d_in[13];
  const float* btf   = (const float*)d_in[14];
  const float* wmos  = (const float*)d_in[15];
  const float* bmos  = (const float*)d_in[16];

  float* out = (float*)d_out;
  float* o_cls = out;                 // 400000 x 3
  float* o_off = out + 1200000;       // 400000 x 3
  float* o_emb = out + 2400000;       // 400000 x 2
  float* o_tf  = out + 3200000;       // 2560 x 7
  float* o_mos = out + 3217920;       // 256 x 1

  char* wsp = (char*)d_ws;
  size_t off = 0;
  auto alloc = [&](size_t bytes) -> void* {
    void* p = wsp + off;
    off = (off + bytes + 255) & ~(size_t)255;
    return p;
  };
  // xt dead after conv -> pf aliases it.
  unsigned short* xt   = (unsigned short*)alloc((size_t)4 * WID * WID * NCI * 2); // 66.4 MB
  unsigned short* pf   = xt;
  unsigned short* wbuf = (unsigned short*)alloc((size_t)9 * 64 * 256 * 2);
  unsigned short* y    = (unsigned short*)alloc((size_t)4 * HW * 64 * 2);         // 16.6 MB
  unsigned short* bev  = (unsigned short*)alloc((size_t)4 * HW * 64 * 2);         // 16.6 MB
  int*   seg      = (int*)alloc((size_t)NPTS * 4);
  int*   rankp    = (int*)alloc((size_t)NPTS * 4);
  int*   order    = (int*)alloc((size_t)NPTS * 4);
  int*   bh       = (int*)alloc((size_t)NSEG * NBLK * 4);   // 1.31 MB
  int*   basebk   = (int*)alloc((size_t)NSEG * NBLK * 4);   // 1.31 MB
  int*   tot      = (int*)alloc(NSEG * 4);
  int*   cnt      = (int*)alloc(NSEG * 4);
  int*   base     = (int*)alloc(NSEG * 4);
  float* part     = (float*)alloc(256 * 64 * 2 * 4);
  float* ab       = (float*)alloc(64 * 2 * 4);
  float* centroid = (float*)alloc(NSEG * 3 * 4);
  float* lf       = (float*)alloc(NSEG * 64 * 4);
  int*   nonem    = (int*)alloc(NSEG * 4);
  float* gf       = (float*)alloc(NINST * 64 * 4);
  float* tc       = (float*)alloc(NINST * 3 * 4);
  float* ic       = (float*)alloc(NINST * 3 * 4);
  float* zbuf     = (float*)alloc(2048);
  (void)ws_size; (void)n_in; (void)in_sizes; (void)out_size;

  hipMemsetAsync(zbuf, 0, 2048, stream);

  k_hist2<<<NBLK, 256, 0, stream>>>(pts, seg, rankp, bh);
  k_scan2a<<<10, 256, 0, stream>>>(bh, basebk, tot);
  k_scan2b<<<1, 256, 0, stream>>>(tot, base, cnt);
  k_scatter2<<<(NPTS + 255) / 256, 256, 0, stream>>>(seg, rankp, base, basebk, order);
  k_transpose<<<dim3(12, WID, 4), 256, 0, stream>>>(x, xt);
  k_wreorg<<<576, 256, 0, stream>>>(convw, wbuf);
  k_conv_mfma<<<1440, 256, 0, stream>>>(xt, wbuf, zbuf, y);
  k_stats2<<<256, 256, 0, stream>>>(y, part);
  k_bnparams<<<1, 64, 0, stream>>>(part, gamma, beta, ab);
  k_bn2<<<(4 * HW * 8 + 255) / 256, 256, 0, stream>>>(y, ab, bev);
  k_points<<<25000, 256, 0, stream>>>(pts, bev, pf);
  k_heads<<<(NPTS + 255) / 256, 256, 0, stream>>>(pf, wseg, bseg, wreg, breg, wemb, bemb,
                                                  o_cls, o_off, o_emb);
  k_seg<<<NSEG, 256, 0, stream>>>(cnt, base, order, pts, pf, wsh, bsh, lf, centroid, nonem);
  k_glob<<<NINST, 64, 0, stream>>>(lf, nonem, centroid, wmos, bmos, gf, tc, ic, o_mos);
  k_tf<<<(NSEG + 255) / 256, 256, 0, stream>>>(lf, gf, centroid, tc, wtf, btf, o_tf);
}

// Round 7
// 376.659 us; speedup vs baseline: 5.1006x; 1.0105x over previous
//
#include <hip/hip_runtime.h>

typedef __attribute__((ext_vector_type(8))) unsigned short u16x8;
typedef __attribute__((ext_vector_type(8))) short s16x8;
typedef __attribute__((ext_vector_type(4))) float f32x4;

#define NPTS 400000
#define HW 32400
#define WID 180
#define NCI 256
#define NCO 64
#define NSEG 2560
#define NINST 256
#define NBLK 128
#define PPB 3125   // NBLK * PPB = 400000

__device__ __forceinline__ float bf2f(unsigned short u) {
  union { unsigned int i; float f; } v; v.i = ((unsigned int)u) << 16; return v.f;
}
__device__ __forceinline__ unsigned short f2bf(float f) {
  unsigned int u = __float_as_uint(f);
  return (unsigned short)((u + 0x7fffu + ((u >> 16) & 1u)) >> 16);
}

__device__ __forceinline__ void gld_lds16(const void* g, void* l) {
  __builtin_amdgcn_global_load_lds((const __attribute__((address_space(1))) void*)g,
                                   (__attribute__((address_space(3))) void*)l, 16, 0, 0);
}

// ---------------- K0: NCHW fp32 -> NHWC bf16 transpose ----------------
__global__ __launch_bounds__(256) void k_transpose(const float* __restrict__ x,
                                                   unsigned short* __restrict__ xt) {
  const int bw = blockIdx.x;            // 0..11: wtile = bw>>2, citile = bw&3
  const int h = blockIdx.y, b = blockIdx.z;
  const int w0 = (bw >> 2) * 64, ci0 = (bw & 3) * 64;
  __shared__ float tile[64][66];
  const int tid = threadIdx.x;
  const int tx = tid & 63, ty = tid >> 6;
  for (int cc = 0; cc < 16; ++cc) {
    int cl = cc * 4 + ty;
    float v = 0.f;
    int w = w0 + tx;
    if (w < WID) v = x[((size_t)(b * NCI + ci0 + cl) * WID + h) * WID + w];
    tile[tx][cl] = v;
  }
  __syncthreads();
  const int tx2 = tid & 31, ty2 = tid >> 5;
  for (int pp = 0; pp < 8; ++pp) {
    int wl = pp * 8 + ty2;
    int w = w0 + wl;
    if (w >= WID) continue;
    float f0 = tile[wl][2 * tx2], f1 = tile[wl][2 * tx2 + 1];
    unsigned int packed = (unsigned int)f2bf(f0) | ((unsigned int)f2bf(f1) << 16);
    *(unsigned int*)(xt + ((size_t)((b * WID + h) * WID + w)) * NCI + ci0 + 2 * tx2) = packed;
  }
}

// ---------------- K0b: conv_w [64][256][3][3] f32 -> wb[tap][co][ci] bf16 ----------------
__global__ void k_wreorg(const float* __restrict__ wt, unsigned short* __restrict__ wb) {
  int id = blockIdx.x * 256 + threadIdx.x;
  if (id >= 9 * 64 * 256) return;
  int ci = id & 255, co = (id >> 8) & 63, tap = id >> 14;
  wb[id] = f2bf(wt[((size_t)co * 256 + ci) * 9 + tap]);
}

// ---------------- K1: implicit-GEMM conv ----------------
// 32-ci chunks (8 total), linear LDS [3][98][4][16B] = 18816B (+pad 19456),
// double-buffered = 38.9KB -> 4 blocks/CU. Subslot XOR swizzle q = lk ^ ((wp>>1)&3)
// applied on BOTH global source and ds_read (rule #21) -> 2-way banks (free).
#define RBUF 19456
#define ROWB 6272   // 98 * 64
__global__ __launch_bounds__(256, 4) void k_conv_mfma(const unsigned short* __restrict__ xt,
                                                   const unsigned short* __restrict__ wb,
                                                   const float* __restrict__ zbuf,
                                                   unsigned short* __restrict__ y) {
  const int wg = blockIdx.x;                    // 0..1439
  const int lin = (wg & 7) * 180 + (wg >> 3);   // bijective: 1440 = 8*180
  const int h = lin % 180;
  const int t2 = lin / 180;                     // b*2 + wth
  const int wth = t2 & 1, b = t2 >> 1;
  const int w0 = wth * 96;
  __shared__ unsigned char strip[2][RBUF];
  const int tid = threadIdx.x;
  const int lane = tid & 63, wv = tid >> 6;
  const int mh = wv >> 1, nh = wv & 1;
  const int l15 = lane & 15, lk = lane >> 4;

  // per-lane pre-swizzled global sources for the 19 block-wide staging loads
  const char* srcs[5];
#pragma unroll
  for (int k = 0; k < 5; ++k) {
    int j = wv + k * 4;
    int g = j * 64 + lane;          // 16B-unit index
    int pxlin = g >> 2, sub = g & 3;
    int row = pxlin / 98;
    int px = pxlin - row * 98;
    int hh = h + row - 1;
    int worig = w0 + px - 1;
    bool valid = (j < 19) && (pxlin < 294) &&
                 (hh >= 0) && (hh < WID) && (worig >= 0) && (worig < WID);
    int cig = sub ^ ((px >> 1) & 3);
    srcs[k] = valid
        ? (const char*)(xt + ((size_t)((b * WID + hh) * WID + worig)) * NCI + cig * 8)
        : (const char*)zbuf + lane * 16;   // +chunk*64 stays inside 2KB
  }

  f32x4 acc[3][2];
#pragma unroll
  for (int i = 0; i < 3; ++i)
#pragma unroll
    for (int j = 0; j < 2; ++j) { acc[i][j][0] = 0.f; acc[i][j][1] = 0.f; acc[i][j][2] = 0.f; acc[i][j][3] = 0.f; }

  auto stage = [&](unsigned char* buf, int chunk) {
#pragma unroll
    for (int k = 0; k < 5; ++k) {
      int j = wv + k * 4;
      if (j >= 19) break;            // wave-uniform (only wv=3,k=4)
      gld_lds16(srcs[k] + chunk * 64, buf + j * 1024);
    }
  };

  stage(strip[0], 0);
  asm volatile("s_waitcnt vmcnt(0)" ::: "memory");
  __syncthreads();

  const unsigned short* wco[2];
#pragma unroll
  for (int nf = 0; nf < 2; ++nf)
    wco[nf] = wb + (size_t)((nh * 2 + nf) * 16 + l15) * 256 + lk * 8;

  for (int chunk = 0; chunk < 8; ++chunk) {
    if (chunk < 7) stage(strip[(chunk + 1) & 1], chunk + 1);
    const unsigned char* buf = strip[chunk & 1];
    s16x8 bfr[9][2];
#pragma unroll
    for (int tap = 0; tap < 9; ++tap)
#pragma unroll
      for (int nf = 0; nf < 2; ++nf)
        bfr[tap][nf] = *(const s16x8*)(wco[nf] + (size_t)tap * (64 * 256) + chunk * 32);
#pragma unroll
    for (int tap = 0; tap < 9; ++tap) {
      const int dh = tap / 3, dw = tap % 3;
      s16x8 afr[3];
#pragma unroll
      for (int i = 0; i < 3; ++i) {
        int wp = (mh * 3 + i) * 16 + l15 + dw;
        int byte = dh * ROWB + wp * 64 + ((lk ^ ((wp >> 1) & 3)) * 16);
        afr[i] = *(const s16x8*)(buf + byte);
      }
#pragma unroll
      for (int i = 0; i < 3; ++i)
#pragma unroll
        for (int nf = 0; nf < 2; ++nf)
          acc[i][nf] = __builtin_amdgcn_mfma_f32_16x16x32_bf16(afr[i], bfr[tap][nf], acc[i][nf], 0, 0, 0);
    }
    asm volatile("s_waitcnt vmcnt(0)" ::: "memory");
    __syncthreads();
  }

  const int r4 = lk * 4;
#pragma unroll
  for (int i = 0; i < 3; ++i) {
#pragma unroll
    for (int nf = 0; nf < 2; ++nf) {
      int co = (nh * 2 + nf) * 16 + l15;
#pragma unroll
      for (int j = 0; j < 4; ++j) {
        int w = w0 + (mh * 3 + i) * 16 + r4 + j;
        if (w < WID)
          y[((size_t)(b * HW) + h * WID + w) * 64 + co] = f2bf(acc[i][nf][j]);
      }
    }
  }
}

// ---------------- K2: BN partial stats over NHWC bf16 y ----------------
__global__ void k_stats2(const unsigned short* __restrict__ y, float* __restrict__ part) {
  const int t = threadIdx.x;
  const int c2 = (t & 31) * 2;
  const int g = t >> 5;
  float s0 = 0.f, s1 = 0.f, ss0 = 0.f, ss1 = 0.f;
  for (int r = blockIdx.x * 8 + g; r < 4 * HW; r += 256 * 8) {
    unsigned int v = *(const unsigned int*)(y + (size_t)r * 64 + c2);
    float f0 = bf2f((unsigned short)(v & 0xffffu));
    float f1 = bf2f((unsigned short)(v >> 16));
    s0 += f0; ss0 = fmaf(f0, f0, ss0);
    s1 += f1; ss1 = fmaf(f1, f1, ss1);
  }
  __shared__ float ls[8][64], lss[8][64];
  ls[g][c2] = s0; ls[g][c2 + 1] = s1;
  lss[g][c2] = ss0; lss[g][c2 + 1] = ss1;
  __syncthreads();
  if (t < 64) {
    float s = 0.f, ss = 0.f;
    for (int k = 0; k < 8; ++k) { s += ls[k][t]; ss += lss[k][t]; }
    part[(blockIdx.x * 64 + t) * 2] = s;
    part[(blockIdx.x * 64 + t) * 2 + 1] = ss;
  }
}

// ---------------- K2b: final BN scale/shift ----------------
__global__ void k_bnparams(const float* __restrict__ part, const float* __restrict__ gamma,
                           const float* __restrict__ beta, float* __restrict__ ab) {
  const int t = threadIdx.x; // 64
  float s = 0.f, ss = 0.f;
  for (int k = 0; k < 256; ++k) { s += part[(k * 64 + t) * 2]; ss += part[(k * 64 + t) * 2 + 1]; }
  float mu = s / 129600.f;
  float var = ss / 129600.f - mu * mu;
  float a = rsqrtf(var + 1e-5f) * gamma[t];
  ab[t * 2] = a; ab[t * 2 + 1] = beta[t] - mu * a;
}

// ---------------- K3: BN apply + ReLU (elementwise NHWC) ----------------
__global__ void k_bn2(const unsigned short* __restrict__ y, const float* __restrict__ ab,
                      unsigned short* __restrict__ bev) {
  __shared__ float sa[64], sb[64];
  const int t = threadIdx.x;
  if (t < 64) { sa[t] = ab[t * 2]; sb[t] = ab[t * 2 + 1]; }
  __syncthreads();
  size_t id = (size_t)blockIdx.x * 256 + t;
  if (id >= (size_t)4 * HW * 8) return;
  int c0 = (int)(id & 7) * 8;
  u16x8 v = *(const u16x8*)(y + id * 8);
  u16x8 o;
#pragma unroll
  for (int k = 0; k < 8; ++k) {
    float f = fmaf(bf2f(v[k]), sa[c0 + k], sb[c0 + k]);
    o[k] = f2bf(f > 0.f ? f : 0.f);
  }
  *(u16x8*)(bev + id * 8) = o;
}

// ---------------- K4: pure bilinear gather, 4 points/wave, no atomics ----------------
__global__ __launch_bounds__(256) void k_points(const float* __restrict__ pts,
                         const unsigned short* __restrict__ bev,
                         unsigned short* __restrict__ pf) {
  const int gid = blockIdx.x * 256 + threadIdx.x;
  const int lane = gid & 63;
  const int wid = gid >> 6;
#pragma unroll
  for (int it = 0; it < 4; ++it) {
    int p = wid * 4 + it;  // exactly covers 400000
    const float* pr = pts + (size_t)p * 9;
    float pbf = pr[0], xx = pr[1], yy = pr[2];
    int b = (int)pbf;
    float px = (xx - (-54.0f)) / 0.6f;
    float py = (yy - (-54.0f)) / 0.6f;
    int x0 = (int)floorf(px); x0 = min(max(x0, 0), WID - 1);
    int x1 = min(x0 + 1, WID - 1);
    int y0 = (int)floorf(py); y0 = min(max(y0, 0), WID - 1);
    int y1 = min(y0 + 1, WID - 1);
    float x0f = (float)x0, x1f = (float)x1, y0f = (float)y0, y1f = (float)y1;
    float wa = (x1f - px) * (y1f - py);
    float wb = (x1f - px) * (py - y0f);
    float wc = (px - x0f) * (y1f - py);
    float wd = (px - x0f) * (py - y0f);
    int i00 = y0 * WID + x0;
    int dx = x1 - x0;
    int dy = (y1 - y0) * WID;
    const unsigned short* bb = bev + ((size_t)b * HW) * 64 + lane;
    float Ia = bf2f(bb[(size_t)i00 * 64]);
    float Ic = bf2f(bb[(size_t)(i00 + dx) * 64]);
    float Ib = bf2f(bb[(size_t)(i00 + dy) * 64]);
    float Id = bf2f(bb[(size_t)(i00 + dy + dx) * 64]);
    float f = wa * Ia + wb * Ib + wc * Ic + wd * Id;
    pf[(size_t)p * 64 + lane] = f2bf(f);
  }
}

// ---------------- K4b: point heads (cls/offset/embedding) ----------------
__global__ void k_heads(const unsigned short* __restrict__ pf,
                        const float* __restrict__ wseg, const float* __restrict__ bseg,
                        const float* __restrict__ wreg, const float* __restrict__ breg,
                        const float* __restrict__ wemb, const float* __restrict__ bemb,
                        float* __restrict__ ocls, float* __restrict__ ooff, float* __restrict__ oemb) {
  const int p = blockIdx.x * 256 + threadIdx.x;
  if (p >= NPTS) return;
  float a0 = bseg[0], a1 = bseg[1], a2 = bseg[2];
  float r0 = breg[0], r1 = breg[1], r2 = breg[2];
  float e0 = bemb[0], e1 = bemb[1];
  const u16x8* q = (const u16x8*)(pf + (size_t)p * 64);
#pragma unroll
  for (int g = 0; g < 8; ++g) {
    u16x8 v8 = q[g];
#pragma unroll
    for (int k = 0; k < 8; ++k) {
      int kk = g * 8 + k;
      float v = bf2f(v8[k]);
      a0 = fmaf(v, wseg[kk * 3 + 0], a0);
      a1 = fmaf(v, wseg[kk * 3 + 1], a1);
      a2 = fmaf(v, wseg[kk * 3 + 2], a2);
      r0 = fmaf(v, wreg[kk * 3 + 0], r0);
      r1 = fmaf(v, wreg[kk * 3 + 1], r1);
      r2 = fmaf(v, wreg[kk * 3 + 2], r2);
      e0 = fmaf(v, wemb[kk * 2 + 0], e0);
      e1 = fmaf(v, wemb[kk * 2 + 1], e1);
    }
  }
  ocls[p * 3 + 0] = a0; ocls[p * 3 + 1] = a1; ocls[p * 3 + 2] = a2;
  ooff[p * 3 + 0] = r0; ooff[p * 3 + 1] = r1; ooff[p * 3 + 2] = r2;
  oemb[p * 2 + 0] = e0; oemb[p * 2 + 1] = e1;
}

// ---------------- K5: LDS-privatized histogram + local rank ----------------
__global__ __launch_bounds__(256) void k_hist2(const float* __restrict__ pts,
                                               int* __restrict__ seg, int* __restrict__ rankp,
                                               int* __restrict__ bh) {
  __shared__ int lc[NSEG];
  const int t = threadIdx.x, blk = blockIdx.x;
  for (int i = t; i < NSEG; i += 256) lc[i] = 0;
  __syncthreads();
  const int p0 = blk * PPB;
  for (int i = t; i < PPB; i += 256) {
    int p = p0 + i;
    const float* pr = pts + (size_t)p * 9;
    int b = (int)pr[0];
    int sw = (int)pr[6];
    int ins = (int)pr[7];
    int s = (b * 64 + ins) * 10 + sw;
    seg[p] = s;
    rankp[p] = atomicAdd(&lc[s], 1);
  }
  __syncthreads();
  for (int i = t; i < NSEG; i += 256) bh[i * NBLK + blk] = lc[i];
}

// ---------------- K6a: per-segment prefix across blocks ----------------
__global__ void k_scan2a(const int* __restrict__ bh, int* __restrict__ basebk,
                         int* __restrict__ tot) {
  const int s = blockIdx.x * 256 + threadIdx.x;  // 0..2559
  int acc = 0;
  for (int b = 0; b < NBLK; ++b) {
    int v = bh[s * NBLK + b];
    basebk[s * NBLK + b] = acc;
    acc += v;
  }
  tot[s] = acc;
}

// ---------------- K6b: exclusive scan of segment totals ----------------
__global__ void k_scan2b(const int* __restrict__ tot, int* __restrict__ base,
                         int* __restrict__ cnt) {
  __shared__ int csum[256];
  const int t = threadIdx.x;
  int loc[10]; int run = 0;
#pragma unroll
  for (int k = 0; k < 10; ++k) { loc[k] = tot[t * 10 + k]; run += loc[k]; }
  csum[t] = run;
  __syncthreads();
  if (t == 0) {
    int a = 0;
    for (int i = 0; i < 256; ++i) { int v = csum[i]; csum[i] = a; a += v; }
  }
  __syncthreads();
  int acc = csum[t];
#pragma unroll
  for (int k = 0; k < 10; ++k) {
    int s = t * 10 + k;
    base[s] = acc; cnt[s] = loc[k];
    acc += loc[k];
  }
}

// ---------------- K7: atomic-free scatter ----------------
__global__ void k_scatter2(const int* __restrict__ seg, const int* __restrict__ rankp,
                           const int* __restrict__ base, const int* __restrict__ basebk,
                           int* __restrict__ order) {
  const int p = blockIdx.x * 256 + threadIdx.x;
  if (p < NPTS) {
    int s = seg[p];
    int blk = p / PPB;
    order[base[s] + basebk[s * NBLK + blk] + rankp[p]] = p;
  }
}

// ---------------- K8: per-segment centroid + shape max + feat max (4 waves) ----------------
__global__ __launch_bounds__(256) void k_seg(const int* __restrict__ cnt, const int* __restrict__ base,
                      const int* __restrict__ order, const float* __restrict__ pts,
                      const unsigned short* __restrict__ pf,
                      const float* __restrict__ wsh, const float* __restrict__ bsh,
                      float* __restrict__ lf, float* __restrict__ centroid,
                      int* __restrict__ nonempty) {
  const int s = blockIdx.x;
  const int t = threadIdx.x, lane = t & 63, wv = t >> 6;
  const int n = cnt[s], bs = base[s];
  float sx = 0.f, sy = 0.f, sz = 0.f;
  for (int i = t; i < n; i += 256) {
    int p = order[bs + i];
    const float* pr = pts + (size_t)p * 9;
    sx += pr[1]; sy += pr[2]; sz += pr[3];
  }
#pragma unroll
  for (int m = 32; m > 0; m >>= 1) {
    sx += __shfl_xor(sx, m); sy += __shfl_xor(sy, m); sz += __shfl_xor(sz, m);
  }
  __shared__ float red[3][4];
  __shared__ float csh[3];
  if (lane == 0) { red[0][wv] = sx; red[1][wv] = sy; red[2][wv] = sz; }
  __syncthreads();
  if (t == 0) {
    float dn = (float)max(n, 1);
    csh[0] = (red[0][0] + red[0][1] + red[0][2] + red[0][3]) / dn;
    csh[1] = (red[1][0] + red[1][1] + red[1][2] + red[1][3]) / dn;
    csh[2] = (red[2][0] + red[2][1] + red[2][2] + red[2][3]) / dn;
  }
  __syncthreads();
  const float cx = csh[0], cy = csh[1], cz = csh[2];
  const float w0 = wsh[lane], w1 = wsh[64 + lane], w2 = wsh[128 + lane], bb = bsh[lane];
  float smax = -INFINITY, lmax = -INFINITY;
  for (int i = wv; i < n; i += 4) {
    int p = order[bs + i];
    const float* pr = pts + (size_t)p * 9;
    float sv = fmaf(pr[1] - cx, w0, fmaf(pr[2] - cy, w1, fmaf(pr[3] - cz, w2, bb)));
    smax = fmaxf(smax, sv);
    lmax = fmaxf(lmax, bf2f(pf[(size_t)p * 64 + lane]));
  }
  __shared__ float rs[4][64], rl[4][64];
  rs[wv][lane] = smax; rl[wv][lane] = lmax;
  __syncthreads();
  if (wv == 0) {
    smax = fmaxf(fmaxf(rs[0][lane], rs[1][lane]), fmaxf(rs[2][lane], rs[3][lane]));
    lmax = fmaxf(fmaxf(rl[0][lane], rl[1][lane]), fmaxf(rl[2][lane], rl[3][lane]));
    bool ne = n > 0;
    lf[s * 64 + lane] = (ne ? lmax : 0.f) + (ne ? smax : 0.f);
    if (lane == 0) {
      nonempty[s] = ne ? 1 : 0;
      centroid[s * 3 + 0] = cx; centroid[s * 3 + 1] = cy; centroid[s * 3 + 2] = cz;
    }
  }
}

// ---------------- K9: per-instance globals + sweep min/max + inst_mos ----------------
__global__ void k_glob(const float* __restrict__ lf, const int* __restrict__ ne,
                       const float* __restrict__ centroid,
                       const float* __restrict__ wmos, const float* __restrict__ bmos,
                       float* __restrict__ gf, float* __restrict__ tc, float* __restrict__ ic,
                       float* __restrict__ omos) {
  const int i = blockIdx.x;
  const int t = threadIdx.x; // 64 threads
  float g = -INFINITY;
  int maxsw = -1, minsw = 10;
  bool any = false;
#pragma unroll
  for (int s = 0; s < 10; ++s) {
    int idx = i * 10 + s;
    bool e = ne[idx] != 0;
    float v = lf[idx * 64 + t];
    g = fmaxf(g, e ? v : -INFINITY);
    if (e) { any = true; maxsw = s; minsw = min(minsw, s); }
  }
  float gv = any ? g : 0.f;
  gf[i * 64 + t] = gv;
  int idxmax = min(max(i * 10 + maxsw, 0), NSEG - 1);
  int idxmin = min(max(i * 10 + minsw, 0), NSEG - 1);
  float tcx = centroid[idxmax * 3 + 0], tcy = centroid[idxmax * 3 + 1], tcz = centroid[idxmax * 3 + 2];
  float icx = centroid[idxmin * 3 + 0], icy = centroid[idxmin * 3 + 1], icz = centroid[idxmin * 3 + 2];
  if (t == 0) {
    tc[i * 3 + 0] = tcx; tc[i * 3 + 1] = tcy; tc[i * 3 + 2] = tcz;
    ic[i * 3 + 0] = icx; ic[i * 3 + 1] = icy; ic[i * 3 + 2] = icz;
  }
  float r = gv * wmos[t];
#pragma unroll
  for (int m = 32; m > 0; m >>= 1) r += __shfl_xor(r, m);
  if (t == 0) {
    r += icx * wmos[64] + icy * wmos[65] + icz * wmos[66];
    r += tcx * wmos[67] + tcy * wmos[68] + tcz * wmos[69];
    omos[i] = r + bmos[0];
  }
}

// ---------------- K10: locals_tf = locals_cat(134) @ w_tf(134x7) ----------------
__global__ void k_tf(const float* __restrict__ lf, const float* __restrict__ gf,
                     const float* __restrict__ centroid, const float* __restrict__ tc,
                     const float* __restrict__ wtf, const float* __restrict__ btf,
                     float* __restrict__ otf) {
  const int r = blockIdx.x * 256 + threadIdx.x;
  if (r >= NSEG) return;
  const int i = r / 10;
  float acc[7];
#pragma unroll
  for (int j = 0; j < 7; ++j) acc[j] = btf[j];
  for (int k = 0; k < 64; ++k) {
    float v = lf[r * 64 + k];
#pragma unroll
    for (int j = 0; j < 7; ++j) acc[j] = fmaf(v, wtf[k * 7 + j], acc[j]);
  }
  for (int k = 0; k < 64; ++k) {
    float v = gf[i * 64 + k];
#pragma unroll
    for (int j = 0; j < 7; ++j) acc[j] = fmaf(v, wtf[(64 + k) * 7 + j], acc[j]);
  }
#pragma unroll
  for (int c = 0; c < 3; ++c) {
    float v = centroid[r * 3 + c];
#pragma unroll
    for (int j = 0; j < 7; ++j) acc[j] = fmaf(v, wtf[(128 + c) * 7 + j], acc[j]);
  }
#pragma unroll
  for (int c = 0; c < 3; ++c) {
    float v = tc[i * 3 + c];
#pragma unroll
    for (int j = 0; j < 7; ++j) acc[j] = fmaf(v, wtf[(131 + c) * 7 + j], acc[j]);
  }
#pragma unroll
  for (int j = 0; j < 7; ++j) otf[r * 7 + j] = acc[j];
}

extern "C" void kernel_launch(void* const* d_in, const int* in_sizes, int n_in,
                              void* d_out, int out_size, void* d_ws, size_t ws_size,
                              hipStream_t stream) {
  const float* pts   = (const float*)d_in[0];
  const float* x     = (const float*)d_in[1];
  const float* convw = (const float*)d_in[2];
  const float* gamma = (const float*)d_in[3];
  const float* beta  = (const float*)d_in[4];
  const float* wseg  = (const float*)d_in[5];
  const float* bseg  = (const float*)d_in[6];
  const float* wreg  = (const float*)d_in[7];
  const float* breg  = (const float*)d_in[8];
  const float* wemb  = (const float*)d_in[9];
  const float* bemb  = (const float*)d_in[10];
  const float* wsh   = (const float*)d_in[11];
  const float* bsh   = (const float*)d_in[12];
  const float* wtf   = (const float*)d_in[13];
  const float* btf   = (const float*)d_in[14];
  const float* wmos  = (const float*)d_in[15];
  const float* bmos  = (const float*)d_in[16];

  float* out = (float*)d_out;
  float* o_cls = out;                 // 400000 x 3
  float* o_off = out + 1200000;       // 400000 x 3
  float* o_emb = out + 2400000;       // 400000 x 2
  float* o_tf  = out + 3200000;       // 2560 x 7
  float* o_mos = out + 3217920;       // 256 x 1

  char* wsp = (char*)d_ws;
  size_t off = 0;
  auto alloc = [&](size_t bytes) -> void* {
    void* p = wsp + off;
    off = (off + bytes + 255) & ~(size_t)255;
    return p;
  };
  // xt dead after conv -> pf aliases it.
  unsigned short* xt   = (unsigned short*)alloc((size_t)4 * WID * WID * NCI * 2); // 66.4 MB
  unsigned short* pf   = xt;
  unsigned short* wbuf = (unsigned short*)alloc((size_t)9 * 64 * 256 * 2);
  unsigned short* y    = (unsigned short*)alloc((size_t)4 * HW * 64 * 2);         // 16.6 MB
  unsigned short* bev  = (unsigned short*)alloc((size_t)4 * HW * 64 * 2);         // 16.6 MB
  int*   seg      = (int*)alloc((size_t)NPTS * 4);
  int*   rankp    = (int*)alloc((size_t)NPTS * 4);
  int*   order    = (int*)alloc((size_t)NPTS * 4);
  int*   bh       = (int*)alloc((size_t)NSEG * NBLK * 4);   // 1.31 MB
  int*   basebk   = (int*)alloc((size_t)NSEG * NBLK * 4);   // 1.31 MB
  int*   tot      = (int*)alloc(NSEG * 4);
  int*   cnt      = (int*)alloc(NSEG * 4);
  int*   base     = (int*)alloc(NSEG * 4);
  float* part     = (float*)alloc(256 * 64 * 2 * 4);
  float* ab       = (float*)alloc(64 * 2 * 4);
  float* centroid = (float*)alloc(NSEG * 3 * 4);
  float* lf       = (float*)alloc(NSEG * 64 * 4);
  int*   nonem    = (int*)alloc(NSEG * 4);
  float* gf       = (float*)alloc(NINST * 64 * 4);
  float* tc       = (float*)alloc(NINST * 3 * 4);
  float* ic       = (float*)alloc(NINST * 3 * 4);
  float* zbuf     = (float*)alloc(2048);
  (void)ws_size; (void)n_in; (void)in_sizes; (void)out_size;

  hipMemsetAsync(zbuf, 0, 2048, stream);

  k_hist2<<<NBLK, 256, 0, stream>>>(pts, seg, rankp, bh);
  k_scan2a<<<10, 256, 0, stream>>>(bh, basebk, tot);
  k_scan2b<<<1, 256, 0, stream>>>(tot, base, cnt);
  k_scatter2<<<(NPTS + 255) / 256, 256, 0, stream>>>(seg, rankp, base, basebk, order);
  k_transpose<<<dim3(12, WID, 4), 256, 0, stream>>>(x, xt);
  k_wreorg<<<576, 256, 0, stream>>>(convw, wbuf);
  k_conv_mfma<<<1440, 256, 0, stream>>>(xt, wbuf, zbuf, y);
  k_stats2<<<256, 256, 0, stream>>>(y, part);
  k_bnparams<<<1, 64, 0, stream>>>(part, gamma, beta, ab);
  k_bn2<<<(4 * HW * 8 + 255) / 256, 256, 0, stream>>>(y, ab, bev);
  k_points<<<25000, 256, 0, stream>>>(pts, bev, pf);
  k_heads<<<(NPTS + 255) / 256, 256, 0, stream>>>(pf, wseg, bseg, wreg, breg, wemb, bemb,
                                                  o_cls, o_off, o_emb);
  k_seg<<<NSEG, 256, 0, stream>>>(cnt, base, order, pts, pf, wsh, bsh, lf, centroid, nonem);
  k_glob<<<NINST, 64, 0, stream>>>(lf, nonem, centroid, wmos, bmos, gf, tc, ic, o_mos);
  k_tf<<<(NSEG + 255) / 256, 256, 0, stream>>>(lf, gf, centroid, tc, wtf, btf, o_tf);
}